// Round 9
// baseline (500.807 us; speedup 1.0000x reference)
//
#include <hip/hip_runtime.h>

typedef unsigned short u16;
typedef __attribute__((ext_vector_type(8))) short short8;
typedef __attribute__((ext_vector_type(4))) float floatx4;
typedef __attribute__((ext_vector_type(2))) float floatx2;

__device__ __forceinline__ float b2f(unsigned int ubits) {
  union { unsigned int i; float f; } cv; cv.i = ubits << 16; return cv.f;
}
__device__ __forceinline__ float hi2f(unsigned int u) {
  union { unsigned int i; float f; } cv; cv.i = u & 0xffff0000u; return cv.f;
}
__device__ __forceinline__ float lo2f(unsigned int u) {
  union { unsigned int i; float f; } cv; cv.i = u << 16; return cv.f;
}
__device__ __forceinline__ u16 f2b(float f) {
  unsigned int u = __builtin_bit_cast(unsigned int, f);
  u += 0x7fffu + ((u >> 16) & 1u);   // RNE
  return (u16)(u >> 16);
}
__device__ __forceinline__ float lrelu(float v) { return v > 0.f ? v : 0.2f * v; }
__device__ __forceinline__ float rdf(bool isbf, const void* p, int idx) {
  return isbf ? b2f((unsigned int)((const u16*)p)[idx]) : ((const float*)p)[idx];
}
__device__ __forceinline__ floatx2 up2(unsigned int u) {
  return (floatx2){lo2f(u), hi2f(u)};   // (even feat, odd feat) -> v_pk_add_f32
}

// ---------------- init: zero deg + colarr pad (48) + dtype detect (block 0) ----------------
__global__ __launch_bounds__(256) void init_kernel(int* __restrict__ deg, int n,
                                                   const u16* __restrict__ probe,
                                                   int* __restrict__ flag,
                                                   int* __restrict__ colarr, int E) {
  int i0 = (blockIdx.x * 256 + threadIdx.x) * 4;
  if (i0 + 3 < n) {
    *(int4*)(deg + i0) = make_int4(0, 0, 0, 0);
  } else {
    for (int j = 0; j < 4; j++) if (i0 + j < n) deg[i0 + j] = 0;
  }
  if (blockIdx.x == 0) {
    if (threadIdx.x >= 64 && threadIdx.x < 112) colarr[E + (int)threadIdx.x - 64] = 0;
    if (threadIdx.x < 64) {
      int lane = threadIdx.x;
      int cnt = 0;
      for (int i = lane; i < 256; i += 64) {
        unsigned int u = probe[i];
        unsigned int e = (u >> 7) & 0xFFu;
        if ((u & 0x7fffu) == 0 || (e >= 60 && e <= 191)) cnt++;
      }
#pragma unroll
      for (int off = 32; off; off >>= 1) cnt += __shfl_down(cnt, off, 64);
      if (lane == 0) *flag = (cnt >= 240) ? 1 : 0;
    }
  }
}

// ---------------- CSR build ----------------
__global__ __launch_bounds__(256) void hist_kernel(const int* __restrict__ dst, int E,
                                                   int* __restrict__ deg) {
  int i = blockIdx.x * 256 + threadIdx.x;
  if (i < E) atomicAdd(deg + dst[i], 1);
}

#define SCB 1024  // nodes per scan block (256 thr x 4)

__global__ __launch_bounds__(256) void scan_phaseA(const int* __restrict__ deg,
                                                   int* __restrict__ bsum, int n) {
  int i0 = blockIdx.x * SCB + threadIdx.x * 4;
  int s = 0;
  if (i0 + 3 < n) {
    int4 v = *(const int4*)(deg + i0);
    s = v.x + v.y + v.z + v.w;
  } else {
    for (int j = 0; j < 4; j++) if (i0 + j < n) s += deg[i0 + j];
  }
#pragma unroll
  for (int off = 32; off; off >>= 1) s += __shfl_down(s, off, 64);
  __shared__ int ws4[4];
  int lane = threadIdx.x & 63, wid = threadIdx.x >> 6;
  if (lane == 0) ws4[wid] = s;
  __syncthreads();
  if (threadIdx.x == 0) bsum[blockIdx.x] = ws4[0] + ws4[1] + ws4[2] + ws4[3];
}

__global__ void scan_phaseB(const int* __restrict__ bsum, int* __restrict__ boff,
                            int PB, int* __restrict__ rowptr, int n) {
  int lane = threadIdx.x;  // 64, PB <= 64
  int v = (lane < PB) ? bsum[lane] : 0;
  int incl = v;
#pragma unroll
  for (int off = 1; off < 64; off <<= 1) {
    int t = __shfl_up(incl, off, 64);
    if (lane >= off) incl += t;
  }
  if (lane < PB) boff[lane] = incl - v;
  if (lane == 63) rowptr[n] = incl;
}

__global__ __launch_bounds__(256) void scan_phaseC(const int* __restrict__ deg,
                                                   const int* __restrict__ boff,
                                                   int* __restrict__ rowptr,
                                                   int* __restrict__ cursor, int n) {
  int i0 = blockIdx.x * SCB + threadIdx.x * 4;
  int v0 = 0, v1 = 0, v2 = 0, v3 = 0;
  if (i0 + 3 < n) {
    int4 v = *(const int4*)(deg + i0);
    v0 = v.x; v1 = v.y; v2 = v.z; v3 = v.w;
  } else {
    if (i0 < n) v0 = deg[i0];
    if (i0 + 1 < n) v1 = deg[i0 + 1];
    if (i0 + 2 < n) v2 = deg[i0 + 2];
    if (i0 + 3 < n) v3 = deg[i0 + 3];
  }
  int local = v0 + v1 + v2 + v3;
  int lane = threadIdx.x & 63, wid = threadIdx.x >> 6;
  int incl = local;
#pragma unroll
  for (int off = 1; off < 64; off <<= 1) {
    int t = __shfl_up(incl, off, 64);
    if (lane >= off) incl += t;
  }
  __shared__ int ws4[4];
  if (lane == 63) ws4[wid] = incl;
  __syncthreads();
  int woff = 0;
  for (int w = 0; w < wid; w++) woff += ws4[w];
  int run = boff[blockIdx.x] + woff + incl - local;
  if (i0 < n)     { rowptr[i0] = run;     cursor[i0] = run; }     run += v0;
  if (i0 + 1 < n) { rowptr[i0 + 1] = run; cursor[i0 + 1] = run; } run += v1;
  if (i0 + 2 < n) { rowptr[i0 + 2] = run; cursor[i0 + 2] = run; } run += v2;
  if (i0 + 3 < n) { rowptr[i0 + 3] = run; cursor[i0 + 3] = run; }
}

__global__ __launch_bounds__(256) void fill_kernel(const int* __restrict__ src,
                                                   const int* __restrict__ dst, int E,
                                                   int* __restrict__ cursor,
                                                   int* __restrict__ colarr) {
  int i = blockIdx.x * 256 + threadIdx.x;
  if (i < E) {
    int p = atomicAdd(cursor + dst[i], 1);
    colarr[p] = src[i];
  }
}

// -------- all weight transposes in one kernel ----------------------------------------
// segments 0..3 (GEMM B operands): k8-major layout  [K/8][128][8]
// segment 4 (Wm for agg_head): [16][256], rows 8..15 zero (zrow lives there).
struct TWDesc {
  const void* W[5];
  int K[5];
  int Nc[5];
  int base[6];  // u16 offsets
};

__global__ __launch_bounds__(256) void transpose_all(TWDesc d, u16* __restrict__ out,
                                                     const int* __restrict__ flagp) {
  bool isbf = (*flagp != 0);
  int idx = blockIdx.x * 256 + threadIdx.x;
  if (idx >= d.base[5]) return;
  int s = 0;
  while (idx >= d.base[s + 1]) s++;
  int local = idx - d.base[s];
  if (s < 4) {
    int k8 = local >> 10;          // local / (128*8)
    int rem = local & 1023;
    int col = rem >> 3;
    int k7 = rem & 7;
    int k = k8 * 8 + k7;
    out[idx] = f2b(rdf(isbf, d.W[s], k * 128 + col));   // Nc = 128 for all four
  } else {
    int nn = local >> 8;           // local / 256
    int k = local & 255;
    out[idx] = (nn < d.Nc[4]) ? f2b(rdf(isbf, d.W[4], k * d.Nc[4] + nn)) : (u16)0;
  }
}

// ---------------- A-fragment load (runtime dtype, exact-zero -> me) ----------------
__device__ __forceinline__ short8 load_a_me(const void* Av, int lda, const void* me,
                                            int r, int k0, int q, bool isbf) {
  short8 a;
  if (isbf) {
    a = *(const short8*)((const u16*)Av + (long)r * lda + k0 + q * 8);
#pragma unroll
    for (int j = 0; j < 8; j++) {
      if (((u16)a[j] & 0x7fffu) == 0)
        a[j] = (short)((const u16*)me)[k0 + q * 8 + j];
    }
  } else {
    const float* A = (const float*)Av;
    const uint4* p = (const uint4*)(A + (long)r * lda + k0 + q * 8);
    uint4 w0 = p[0];
    uint4 w1 = p[1];
    unsigned int ww[8] = {w0.x, w0.y, w0.z, w0.w, w1.x, w1.y, w1.z, w1.w};
#pragma unroll
    for (int j = 0; j < 8; j++) {
      if ((ww[j] & 0x7fffffffu) == 0)
        a[j] = (short)f2b(((const float*)me)[k0 + q * 8 + j]);
      else
        a[j] = (short)f2b(__builtin_bit_cast(float, ww[j]));
    }
  }
  return a;
}

// ------------- layer-1 GEMM, e/c split across blocks; B staged in LDS (k8-major);
// C written to SLICED layout tsl[slice][N][32] (slice = col>>5) for L2-resident agg.
__global__ __launch_bounds__(256) void gemm_l1(
    const void* __restrict__ x, const void* __restrict__ cc,
    const void* __restrict__ mex, const void* __restrict__ mec,
    const u16* __restrict__ w1e_t, const u16* __restrict__ w1c_t,
    int M, int gb, u16* __restrict__ tsl, const int* __restrict__ flagp) {
  __shared__ __align__(16) u16 bs[32768];  // 64 KB
  bool isbf = (*flagp != 0);
  bool isC = (blockIdx.x >= (unsigned)gb);
  int bid = isC ? (int)blockIdx.x - gb : (int)blockIdx.x;
  int tid = threadIdx.x;
  int wid = tid >> 6;
  int lane = tid & 63;
  int l15 = lane & 15;
  int q = lane >> 4;
  int row0 = bid * 64 + wid * 16;
  int r = row0 + l15;
  if (r >= M) r = M - 1;

  const void* A  = isC ? cc : x;
  const void* me = isC ? mec : mex;
  const u16* wt  = isC ? w1c_t : w1e_t;
  int K    = isC ? 128 : 256;
  int cofs = isC ? 128 : 0;

  // stage B: linear coalesced copy (wt already in [K/8][128][8] order)
  int nchunk = K * 16;  // (128*K)/8 16-byte chunks
  for (int i = tid; i < nchunk; i += 256)
    *(uint4*)(bs + i * 8) = *(const uint4*)(wt + i * 8);
  __syncthreads();

  floatx4 acc[8];
#pragma unroll
  for (int n = 0; n < 8; n++) acc[n] = (floatx4){0, 0, 0, 0};

  for (int k0 = 0; k0 < K; k0 += 32) {
    short8 a = load_a_me(A, K, me, r, k0, q, isbf);
    const u16* bb = bs + ((k0 >> 3) + q) * 1024 + l15 * 8;
#pragma unroll
    for (int n = 0; n < 8; n++) {
      short8 b = *(const short8*)(bb + n * 128);
      acc[n] = __builtin_amdgcn_mfma_f32_16x16x32_bf16(a, b, acc[n], 0, 0, 0);
    }
  }
#pragma unroll
  for (int n = 0; n < 8; n++) {
    int col = cofs + n * 16;                  // 16-col group never straddles a 32-col slice
    long sbase = (long)(col >> 5) * M * 32;
    int off = (col & 31) + l15;
#pragma unroll
    for (int rr = 0; rr < 4; rr++) {
      int row = row0 + q * 4 + rr;
      if (row < M) tsl[sbase + (long)row * 32 + off] = f2b(acc[n][rr]);
    }
  }
}

// ------------- layer-2 GEMM, e/c split across blocks; B staged in LDS (k8-major, 32KB):
// reads row-major ubuf, writes row-major tbuf (for agg_head).
__global__ __launch_bounds__(256) void gemm_l2(
    const u16* __restrict__ u,
    const u16* __restrict__ w2e_t, const u16* __restrict__ w2c_t,
    int M, int gb, u16* __restrict__ tb) {
  __shared__ __align__(16) u16 bs[16384];  // 32 KB
  bool isC = (blockIdx.x >= (unsigned)gb);
  int bid = isC ? (int)blockIdx.x - gb : (int)blockIdx.x;
  int tid = threadIdx.x;
  int wid = tid >> 6;
  int lane = tid & 63;
  int l15 = lane & 15;
  int q = lane >> 4;
  int row0 = bid * 64 + wid * 16;
  int r = row0 + l15;
  if (r >= M) r = M - 1;

  const u16* wt = isC ? w2c_t : w2e_t;
  int aofs = isC ? 128 : 0;

  for (int i = tid; i < 2048; i += 256)
    *(uint4*)(bs + i * 8) = *(const uint4*)(wt + i * 8);
  __syncthreads();

  floatx4 acc[8];
#pragma unroll
  for (int n = 0; n < 8; n++) acc[n] = (floatx4){0, 0, 0, 0};

  for (int k0 = 0; k0 < 128; k0 += 32) {
    short8 a = *(const short8*)(u + (long)r * 256 + aofs + k0 + q * 8);
    const u16* bb = bs + ((k0 >> 3) + q) * 1024 + l15 * 8;
#pragma unroll
    for (int n = 0; n < 8; n++) {
      short8 b = *(const short8*)(bb + n * 128);
      acc[n] = __builtin_amdgcn_mfma_f32_16x16x32_bf16(a, b, acc[n], 0, 0, 0);
    }
  }
#pragma unroll
  for (int n = 0; n < 8; n++)
#pragma unroll
    for (int rr = 0; rr < 4; rr++) {
      int row = row0 + q * 4 + rr;
      if (row < M) tb[(long)row * 256 + aofs + n * 16 + l15] = f2b(acc[n][rr]);
    }
}

// ------- agg layer-1, COLUMN-SLICED: slice = blockIdx&7 (aligned with XCD round-robin),
// each slice is a contiguous tsl[s][N][32] region (3.2 MB -> fits one XCD's 4 MiB L2).
// Wave: lane = e8*8+f8 -> 8 edges/instr x 64 B segments; 16 edges in flight; per-lane
// tail mask to zero row; shfl_xor cross-slot reduce; writes row-major ubuf. -------
__global__ __launch_bounds__(256) void agg_kernel(
    const u16* __restrict__ tsl, const int* __restrict__ rowptr,
    const int* __restrict__ colarr,
    const void* __restrict__ epsE, const void* __restrict__ epsC,
    const void* __restrict__ bE, const void* __restrict__ bC,
    u16* __restrict__ u, int N, const u16* __restrict__ zrow,
    const int* __restrict__ flagp) {
  int bid = blockIdx.x;
  int s = bid & 7;
  int node = (bid >> 3) * 4 + (threadIdx.x >> 6);
  if (node >= N) return;
  bool isbf = (*flagp != 0);
  int lane = threadIdx.x & 63;
  int e8 = lane >> 3;   // edge slot 0..7
  int f8 = lane & 7;    // feature group (4 feats)
  const char* cbase = (const char*)(tsl + (long)s * N * 32) + f8 * 8;
  const char* zb = (const char*)zrow + f8 * 8;

  uint2 ps = *(const uint2*)(cbase + ((long)node << 6));  // self row, issued early

  floatx2 s01 = (floatx2){0.f, 0.f}, s23 = (floatx2){0.f, 0.f};
  int eu  = __builtin_amdgcn_readfirstlane(rowptr[node]);
  int e1u = __builtin_amdgcn_readfirstlane(rowptr[node + 1]);
  int ei0 = eu + e8, ei1 = eu + 8 + e8;
  int c0 = colarr[ei0];              // 48-entry zero pad makes all reads safe
  int c1 = colarr[ei1];
  for (int eb = eu; eb < e1u; eb += 16) {
    const char* p0 = (eb + e8 < e1u)     ? cbase + ((long)c0 << 6) : zb;
    const char* p1 = (eb + 8 + e8 < e1u) ? cbase + ((long)c1 << 6) : zb;
    uint2 w0 = *(const uint2*)p0;
    uint2 w1 = *(const uint2*)p1;
    int n0 = colarr[ei0 + 16];       // prefetch (<= E+47, inside pad)
    int n1 = colarr[ei1 + 16];
    s01 += up2(w0.x); s23 += up2(w0.y);
    s01 += up2(w1.x); s23 += up2(w1.y);
    c0 = n0; c1 = n1; ei0 += 16; ei1 += 16;
  }
  // reduce across the 8 edge slots
#pragma unroll
  for (int m = 8; m < 64; m <<= 1) {
    s01.x += __shfl_xor(s01.x, m, 64);
    s01.y += __shfl_xor(s01.y, m, 64);
    s23.x += __shfl_xor(s23.x, m, 64);
    s23.y += __shfl_xor(s23.y, m, 64);
  }
  int f0 = s * 32 + f8 * 4;
  bool isE = (s < 4);
  float eps2 = 2.0f + rdf(isbf, isE ? epsE : epsC, 0);
  const void* bp = isE ? bE : bC;
  int bi = isE ? f0 : (f0 - 128);
  float a0 = lrelu(s01.x + eps2 * lo2f(ps.x) + rdf(isbf, bp, bi + 0));
  float a1 = lrelu(s01.y + eps2 * hi2f(ps.x) + rdf(isbf, bp, bi + 1));
  float a2 = lrelu(s23.x + eps2 * lo2f(ps.y) + rdf(isbf, bp, bi + 2));
  float a3 = lrelu(s23.y + eps2 * hi2f(ps.y) + rdf(isbf, bp, bi + 3));
  if (e8 == 0) {
    uint2 o;
    o.x = ((unsigned int)f2b(a1) << 16) | f2b(a0);
    o.y = ((unsigned int)f2b(a3) << 16) | f2b(a2);
    *(uint2*)(u + (long)node * 256 + f0) = o;
  }
}

// ===== row-major gather core for agg_head (depth-8, scalar cols) =====
__device__ __forceinline__ void gin_gather8(
    const u16* __restrict__ t, const int* __restrict__ rowptr,
    const int* __restrict__ colarr, const u16* __restrict__ zrow,
    int node, long fbB, floatx2& s01, floatx2& s23) {
  const char* base = (const char*)t + fbB;   // per-lane feature base
  const char* zb = (const char*)zrow + fbB;  // zero row
  s01 = (floatx2){0.f, 0.f};
  s23 = (floatx2){0.f, 0.f};
  int eu  = __builtin_amdgcn_readfirstlane(rowptr[node]);
  int e1u = __builtin_amdgcn_readfirstlane(rowptr[node + 1]);
  int c0 = colarr[eu],     c1 = colarr[eu + 1], c2 = colarr[eu + 2], c3 = colarr[eu + 3];
  int c4 = colarr[eu + 4], c5 = colarr[eu + 5], c6 = colarr[eu + 6], c7 = colarr[eu + 7];
  int eb = eu;
  for (; eb + 8 <= e1u; eb += 8) {
    uint2 w0 = *(const uint2*)(base + ((long)c0 << 9));
    uint2 w1 = *(const uint2*)(base + ((long)c1 << 9));
    uint2 w2 = *(const uint2*)(base + ((long)c2 << 9));
    uint2 w3 = *(const uint2*)(base + ((long)c3 << 9));
    uint2 w4 = *(const uint2*)(base + ((long)c4 << 9));
    uint2 w5 = *(const uint2*)(base + ((long)c5 << 9));
    uint2 w6 = *(const uint2*)(base + ((long)c6 << 9));
    uint2 w7 = *(const uint2*)(base + ((long)c7 << 9));
    int n0 = colarr[eb + 8],  n1 = colarr[eb + 9],  n2 = colarr[eb + 10], n3 = colarr[eb + 11];
    int n4 = colarr[eb + 12], n5 = colarr[eb + 13], n6 = colarr[eb + 14], n7 = colarr[eb + 15];
    s01 += up2(w0.x); s23 += up2(w0.y);
    s01 += up2(w1.x); s23 += up2(w1.y);
    s01 += up2(w2.x); s23 += up2(w2.y);
    s01 += up2(w3.x); s23 += up2(w3.y);
    s01 += up2(w4.x); s23 += up2(w4.y);
    s01 += up2(w5.x); s23 += up2(w5.y);
    s01 += up2(w6.x); s23 += up2(w6.y);
    s01 += up2(w7.x); s23 += up2(w7.y);
    c0 = n0; c1 = n1; c2 = n2; c3 = n3;
    c4 = n4; c5 = n5; c6 = n6; c7 = n7;
  }
  int rem = e1u - eb;  // 0..7
  if (rem > 0) {
    const char* p0 = base + ((long)c0 << 9);
    const char* p1 = (1 < rem) ? base + ((long)c1 << 9) : zb;
    const char* p2 = (2 < rem) ? base + ((long)c2 << 9) : zb;
    const char* p3 = (3 < rem) ? base + ((long)c3 << 9) : zb;
    const char* p4 = (4 < rem) ? base + ((long)c4 << 9) : zb;
    const char* p5 = (5 < rem) ? base + ((long)c5 << 9) : zb;
    const char* p6 = (6 < rem) ? base + ((long)c6 << 9) : zb;
    const char* p7 = (7 < rem) ? base + ((long)c7 << 9) : zb;
    uint2 w0 = *(const uint2*)p0;
    uint2 w1 = *(const uint2*)p1;
    uint2 w2 = *(const uint2*)p2;
    uint2 w3 = *(const uint2*)p3;
    uint2 w4 = *(const uint2*)p4;
    uint2 w5 = *(const uint2*)p5;
    uint2 w6 = *(const uint2*)p6;
    uint2 w7 = *(const uint2*)p7;
    s01 += up2(w0.x); s23 += up2(w0.y);
    s01 += up2(w1.x); s23 += up2(w1.y);
    s01 += up2(w2.x); s23 += up2(w2.y);
    s01 += up2(w3.x); s23 += up2(w3.y);
    s01 += up2(w4.x); s23 += up2(w4.y);
    s01 += up2(w5.x); s23 += up2(w5.y);
    s01 += up2(w6.x); s23 += up2(w6.y);
    s01 += up2(w7.x); s23 += up2(w7.y);
  }
}

// ------- agg layer-2 + head fused: out[node] = lrelu(u @ Wm + bm) -------
__global__ __launch_bounds__(256) void agg_head(
    const u16* __restrict__ t, const int* __restrict__ rowptr, const int* __restrict__ colarr,
    const void* __restrict__ epsE, const void* __restrict__ epsC,
    const void* __restrict__ bE, const void* __restrict__ bC,
    const u16* __restrict__ wm_t, const void* __restrict__ bm,
    float* __restrict__ out, int N, const u16* __restrict__ zrow,
    const int* __restrict__ flagp) {
  __shared__ float wmf[2048];  // [col][f] f32, from wm_t [16][256] (cols 0..7)
  __shared__ float bmf[8];
  bool isbf = (*flagp != 0);
  int tid = threadIdx.x;
  for (int i = tid; i < 2048; i += 256) wmf[i] = b2f((unsigned int)wm_t[i]);
  if (tid < 8) bmf[tid] = rdf(isbf, bm, tid);
  __syncthreads();

  int node = blockIdx.x * 4 + __builtin_amdgcn_readfirstlane(tid >> 6);
  if (node >= N) return;
  int lane = tid & 63;
  int f0 = lane << 2;
  long fbB = (long)f0 << 1;
  const u16* tb = t + f0;

  uint2 ps = *(const uint2*)(tb + ((long)node << 8));  // self row, issued early

  floatx2 s01, s23;
  gin_gather8(t, rowptr, colarr, zrow, node, fbB, s01, s23);

  bool isE = (lane < 32);
  float eps2 = 2.0f + rdf(isbf, isE ? epsE : epsC, 0);
  const void* bp = isE ? bE : bC;
  int bi = isE ? f0 : (f0 - 128);
  float a0 = lrelu(s01.x + eps2 * lo2f(ps.x) + rdf(isbf, bp, bi + 0));
  float a1 = lrelu(s01.y + eps2 * hi2f(ps.x) + rdf(isbf, bp, bi + 1));
  float a2 = lrelu(s23.x + eps2 * lo2f(ps.y) + rdf(isbf, bp, bi + 2));
  float a3 = lrelu(s23.y + eps2 * hi2f(ps.y) + rdf(isbf, bp, bi + 3));

  // head: p[col] = sum_f u[f] * Wm[f][col]  (per-lane 4-feat partial, then 64-lane butterfly)
  float p[8];
#pragma unroll
  for (int col = 0; col < 8; col++) {
    float4 w = *(const float4*)&wmf[col * 256 + f0];
    p[col] = a0 * w.x + a1 * w.y + a2 * w.z + a3 * w.w;
  }
#pragma unroll
  for (int m = 1; m < 64; m <<= 1) {
#pragma unroll
    for (int col = 0; col < 8; col++) p[col] += __shfl_xor(p[col], m, 64);
  }
  if (lane == 0) {
    float4 o0, o1;
    o0.x = lrelu(p[0] + bmf[0]); o0.y = lrelu(p[1] + bmf[1]);
    o0.z = lrelu(p[2] + bmf[2]); o0.w = lrelu(p[3] + bmf[3]);
    o1.x = lrelu(p[4] + bmf[4]); o1.y = lrelu(p[5] + bmf[5]);
    o1.z = lrelu(p[6] + bmf[6]); o1.w = lrelu(p[7] + bmf[7]);
    *(float4*)(out + (long)node * 8) = o0;
    *(float4*)(out + (long)node * 8 + 4) = o1;
  }
}

// ---------------- central-node MLP (f32 in, f32 out) ----------------
__global__ __launch_bounds__(128) void mlp_kernel(
    const float* __restrict__ outbuf, const int* __restrict__ central,
    const void* __restrict__ Wp1, const void* __restrict__ bp1,
    const void* __restrict__ Wp2, const void* __restrict__ bp2,
    float* __restrict__ logits, const int* __restrict__ flagp) {
  __shared__ float h1[128];
  __shared__ float o[8];
  bool isbf = (*flagp != 0);
  int b = blockIdx.x, tid = threadIdx.x;
  int node = central[b];
  if (tid < 8) o[tid] = outbuf[node * 8 + tid];
  __syncthreads();
  float s = rdf(isbf, bp1, tid);
#pragma unroll
  for (int k = 0; k < 8; k++) s += o[k] * rdf(isbf, Wp1, k * 128 + tid);
  h1[tid] = fmaxf(s, 0.f);
  __syncthreads();
  if (tid < 8) {
    float s2 = rdf(isbf, bp2, tid);
    for (int k = 0; k < 128; k++) s2 += h1[k] * rdf(isbf, Wp2, k * 8 + tid);
    logits[b * 8 + tid] = s2;
  }
}

extern "C" void kernel_launch(void* const* d_in, const int* in_sizes, int n_in,
                              void* d_out, int out_size, void* d_ws, size_t ws_size,
                              hipStream_t stream) {
  const void* x    = d_in[0];
  const void* c    = d_in[1];
  const int* eidx  = (const int*)d_in[2];
  const int* cidx  = (const int*)d_in[3];
  const void* me_x = d_in[4];
  const void* me_c = d_in[5];
  const void* W1e  = d_in[6];
  const void* b1e  = d_in[7];
  const void* e1e  = d_in[8];
  const void* W2e  = d_in[9];
  const void* b2e  = d_in[10];
  const void* e2e  = d_in[11];
  const void* W1c  = d_in[12];
  const void* b1c  = d_in[13];
  const void* e1c  = d_in[14];
  const void* W2c  = d_in[15];
  const void* b2c  = d_in[16];
  const void* e2c  = d_in[17];
  const void* Wm   = d_in[18];
  const void* bm   = d_in[19];
  const void* Wp1  = d_in[20];
  const void* bp1  = d_in[21];
  const void* Wp2  = d_in[22];
  const void* bp2  = d_in[23];

  const int N = in_sizes[0] / 256;   // 50000
  const int E = in_sizes[2] / 2;     // 800000
  const int Cn = in_sizes[3];        // 512
  const int* src = eidx;
  const int* dst = eidx + E;

  char* ws = (char*)d_ws;
  int* deg    = (int*)(ws + 0);          // 200000 B
  int* rowptr = (int*)(ws + 200192);     // 200004 B
  int* cursor = (int*)(ws + 400384);     // 200000 B
  int* colarr = (int*)(ws + 600576);     // 3200000 B + 192 B zero pad
  u16* tbuf   = (u16*)(ws + 3800832);    // 25600000 B  [N,256] bf16 (row-major, layer 2)
  u16* ubuf   = (u16*)(ws + 29400832);   // 25600000 B  [N,256] bf16
  u16* wt_all = (u16*)(ws + 55000832);   // 172032 B
  int* flag   = (int*)(ws + 55172864);   // 4 B
  int* bsum   = (int*)(ws + 55173120);   // 256 B
  int* boff   = (int*)(ws + 55173376);   // 256 B
  u16* tslice = (u16*)(ws + 55173632);   // 25600000 B  [8][N][32] bf16 (sliced, layer 1)

  u16* w1e_t = wt_all + 0;       // [32][128][8]  k8-major, 64 KB
  u16* w1c_t = wt_all + 32768;   // [16][128][8]  k8-major, 32 KB
  u16* w2e_t = wt_all + 49152;   // [16][128][8]
  u16* w2c_t = wt_all + 65536;   // [16][128][8]
  u16* wm_t  = wt_all + 81920;   // [16][256]  (rows 8..15 are zeros)
  const u16* zrow = wt_all + 83968;  // = wm_t + 8*256: guaranteed-zero 512 B row

  // init: zero deg + colarr pad (48 entries) + dtype detect
  init_kernel<<<(N + 1023) / 1024, 256, 0, stream>>>(deg, N, (const u16*)x, flag,
                                                     colarr, E);

  // CSR build
  hist_kernel<<<(E + 255) / 256, 256, 0, stream>>>(dst, E, deg);
  int PB = (N + SCB - 1) / SCB;  // 49
  scan_phaseA<<<PB, 256, 0, stream>>>(deg, bsum, N);
  scan_phaseB<<<1, 64, 0, stream>>>(bsum, boff, PB, rowptr, N);
  scan_phaseC<<<PB, 256, 0, stream>>>(deg, boff, rowptr, cursor, N);
  fill_kernel<<<(E + 255) / 256, 256, 0, stream>>>(src, dst, E, cursor, colarr);

  // weight transposes
  TWDesc td;
  td.W[0] = W1e; td.K[0] = 256; td.Nc[0] = 128;
  td.W[1] = W1c; td.K[1] = 128; td.Nc[1] = 128;
  td.W[2] = W2e; td.K[2] = 128; td.Nc[2] = 128;
  td.W[3] = W2c; td.K[3] = 128; td.Nc[3] = 128;
  td.W[4] = Wm;  td.K[4] = 256; td.Nc[4] = 8;
  td.base[0] = 0; td.base[1] = 32768; td.base[2] = 49152;
  td.base[3] = 65536; td.base[4] = 81920; td.base[5] = 86016;
  transpose_all<<<(86016 + 255) / 256, 256, 0, stream>>>(td, wt_all, flag);

  int gb = (N + 63) / 64;  // 782
  // layer 1 (e/c split; LDS-staged B; sliced C output)
  gemm_l1<<<2 * gb, 256, 0, stream>>>(x, c, me_x, me_c, w1e_t, w1c_t, N, gb, tslice, flag);
  // agg layer 1, column-sliced (slice = bid&7 -> XCD-local L2 working set)
  agg_kernel<<<((N + 3) / 4) * 8, 256, 0, stream>>>(tslice, rowptr, colarr,
      e1e, e1c, b1e, b1c, ubuf, N, zrow, flag);
  // layer 2 (e/c split; LDS-staged B; row-major out)
  gemm_l2<<<2 * gb, 256, 0, stream>>>(ubuf, w2e_t, w2c_t, N, gb, tbuf);
  // agg2 + head fused -> d_out[0 : N*8] f32
  agg_head<<<(N + 3) / 4, 256, 0, stream>>>(tbuf, rowptr, colarr,
      e2e, e2c, b2e, b2c, wm_t, bm, (float*)d_out, N, zrow, flag);
  // central MLP -> d_out[N*8 : ...]
  mlp_kernel<<<Cn, 128, 0, stream>>>((const float*)d_out, cidx,
      Wp1, bp1, Wp2, bp2, (float*)d_out + (size_t)N * 8, flag);
}

// Round 10
// 415.308 us; speedup vs baseline: 1.2059x; 1.2059x over previous
//
#include <hip/hip_runtime.h>

typedef unsigned short u16;
typedef __attribute__((ext_vector_type(8))) short short8;
typedef __attribute__((ext_vector_type(4))) float floatx4;
typedef __attribute__((ext_vector_type(2))) float floatx2;

__device__ __forceinline__ float b2f(unsigned int ubits) {
  union { unsigned int i; float f; } cv; cv.i = ubits << 16; return cv.f;
}
__device__ __forceinline__ float hi2f(unsigned int u) {
  union { unsigned int i; float f; } cv; cv.i = u & 0xffff0000u; return cv.f;
}
__device__ __forceinline__ float lo2f(unsigned int u) {
  union { unsigned int i; float f; } cv; cv.i = u << 16; return cv.f;
}
__device__ __forceinline__ u16 f2b(float f) {
  unsigned int u = __builtin_bit_cast(unsigned int, f);
  u += 0x7fffu + ((u >> 16) & 1u);   // RNE
  return (u16)(u >> 16);
}
__device__ __forceinline__ float lrelu(float v) { return v > 0.f ? v : 0.2f * v; }
__device__ __forceinline__ float rdf(bool isbf, const void* p, int idx) {
  return isbf ? b2f((unsigned int)((const u16*)p)[idx]) : ((const float*)p)[idx];
}
__device__ __forceinline__ floatx2 up2(unsigned int u) {
  return (floatx2){lo2f(u), hi2f(u)};   // (even feat, odd feat) -> v_pk_add_f32
}

// ---------------- init: zero deg + colarr pad (48) + dtype detect (block 0) ----------------
__global__ __launch_bounds__(256) void init_kernel(int* __restrict__ deg, int n,
                                                   const u16* __restrict__ probe,
                                                   int* __restrict__ flag,
                                                   int* __restrict__ colarr, int E) {
  int i0 = (blockIdx.x * 256 + threadIdx.x) * 4;
  if (i0 + 3 < n) {
    *(int4*)(deg + i0) = make_int4(0, 0, 0, 0);
  } else {
    for (int j = 0; j < 4; j++) if (i0 + j < n) deg[i0 + j] = 0;
  }
  if (blockIdx.x == 0) {
    if (threadIdx.x >= 64 && threadIdx.x < 112) colarr[E + (int)threadIdx.x - 64] = 0;
    if (threadIdx.x < 64) {
      int lane = threadIdx.x;
      int cnt = 0;
      for (int i = lane; i < 256; i += 64) {
        unsigned int u = probe[i];
        unsigned int e = (u >> 7) & 0xFFu;
        if ((u & 0x7fffu) == 0 || (e >= 60 && e <= 191)) cnt++;
      }
#pragma unroll
      for (int off = 32; off; off >>= 1) cnt += __shfl_down(cnt, off, 64);
      if (lane == 0) *flag = (cnt >= 240) ? 1 : 0;
    }
  }
}

// ---------------- CSR build ----------------
__global__ __launch_bounds__(256) void hist_kernel(const int* __restrict__ dst, int E,
                                                   int* __restrict__ deg) {
  int i = blockIdx.x * 256 + threadIdx.x;
  if (i < E) atomicAdd(deg + dst[i], 1);
}

#define SCB 1024  // nodes per scan block (256 thr x 4)

__global__ __launch_bounds__(256) void scan_phaseA(const int* __restrict__ deg,
                                                   int* __restrict__ bsum, int n) {
  int i0 = blockIdx.x * SCB + threadIdx.x * 4;
  int s = 0;
  if (i0 + 3 < n) {
    int4 v = *(const int4*)(deg + i0);
    s = v.x + v.y + v.z + v.w;
  } else {
    for (int j = 0; j < 4; j++) if (i0 + j < n) s += deg[i0 + j];
  }
#pragma unroll
  for (int off = 32; off; off >>= 1) s += __shfl_down(s, off, 64);
  __shared__ int ws4[4];
  int lane = threadIdx.x & 63, wid = threadIdx.x >> 6;
  if (lane == 0) ws4[wid] = s;
  __syncthreads();
  if (threadIdx.x == 0) bsum[blockIdx.x] = ws4[0] + ws4[1] + ws4[2] + ws4[3];
}

__global__ void scan_phaseB(const int* __restrict__ bsum, int* __restrict__ boff,
                            int PB, int* __restrict__ rowptr, int n) {
  int lane = threadIdx.x;  // 64, PB <= 64
  int v = (lane < PB) ? bsum[lane] : 0;
  int incl = v;
#pragma unroll
  for (int off = 1; off < 64; off <<= 1) {
    int t = __shfl_up(incl, off, 64);
    if (lane >= off) incl += t;
  }
  if (lane < PB) boff[lane] = incl - v;
  if (lane == 63) rowptr[n] = incl;
}

__global__ __launch_bounds__(256) void scan_phaseC(const int* __restrict__ deg,
                                                   const int* __restrict__ boff,
                                                   int* __restrict__ rowptr,
                                                   int* __restrict__ cursor, int n) {
  int i0 = blockIdx.x * SCB + threadIdx.x * 4;
  int v0 = 0, v1 = 0, v2 = 0, v3 = 0;
  if (i0 + 3 < n) {
    int4 v = *(const int4*)(deg + i0);
    v0 = v.x; v1 = v.y; v2 = v.z; v3 = v.w;
  } else {
    if (i0 < n) v0 = deg[i0];
    if (i0 + 1 < n) v1 = deg[i0 + 1];
    if (i0 + 2 < n) v2 = deg[i0 + 2];
    if (i0 + 3 < n) v3 = deg[i0 + 3];
  }
  int local = v0 + v1 + v2 + v3;
  int lane = threadIdx.x & 63, wid = threadIdx.x >> 6;
  int incl = local;
#pragma unroll
  for (int off = 1; off < 64; off <<= 1) {
    int t = __shfl_up(incl, off, 64);
    if (lane >= off) incl += t;
  }
  __shared__ int ws4[4];
  if (lane == 63) ws4[wid] = incl;
  __syncthreads();
  int woff = 0;
  for (int w = 0; w < wid; w++) woff += ws4[w];
  int run = boff[blockIdx.x] + woff + incl - local;
  if (i0 < n)     { rowptr[i0] = run;     cursor[i0] = run; }     run += v0;
  if (i0 + 1 < n) { rowptr[i0 + 1] = run; cursor[i0 + 1] = run; } run += v1;
  if (i0 + 2 < n) { rowptr[i0 + 2] = run; cursor[i0 + 2] = run; } run += v2;
  if (i0 + 3 < n) { rowptr[i0 + 3] = run; cursor[i0 + 3] = run; }
}

__global__ __launch_bounds__(256) void fill_kernel(const int* __restrict__ src,
                                                   const int* __restrict__ dst, int E,
                                                   int* __restrict__ cursor,
                                                   int* __restrict__ colarr) {
  int i = blockIdx.x * 256 + threadIdx.x;
  if (i < E) {
    int p = atomicAdd(cursor + dst[i], 1);
    colarr[p] = src[i];
  }
}

// -------- all weight transposes in one kernel ----------------------------------------
// segments 0..3 (GEMM B operands): k8-major layout  [K/8][128][8]
// segment 4 (Wm for agg_head): [16][256], rows 8..15 zero (zrow lives there).
struct TWDesc {
  const void* W[5];
  int K[5];
  int Nc[5];
  int base[6];  // u16 offsets
};

__global__ __launch_bounds__(256) void transpose_all(TWDesc d, u16* __restrict__ out,
                                                     const int* __restrict__ flagp) {
  bool isbf = (*flagp != 0);
  int idx = blockIdx.x * 256 + threadIdx.x;
  if (idx >= d.base[5]) return;
  int s = 0;
  while (idx >= d.base[s + 1]) s++;
  int local = idx - d.base[s];
  if (s < 4) {
    int k8 = local >> 10;          // local / (128*8)
    int rem = local & 1023;
    int col = rem >> 3;
    int k7 = rem & 7;
    int k = k8 * 8 + k7;
    out[idx] = f2b(rdf(isbf, d.W[s], k * 128 + col));   // Nc = 128 for all four
  } else {
    int nn = local >> 8;           // local / 256
    int k = local & 255;
    out[idx] = (nn < d.Nc[4]) ? f2b(rdf(isbf, d.W[4], k * d.Nc[4] + nn)) : (u16)0;
  }
}

// ---------------- A-fragment load (runtime dtype, exact-zero -> me) ----------------
__device__ __forceinline__ short8 load_a_me(const void* Av, int lda, const void* me,
                                            int r, int k0, int q, bool isbf) {
  short8 a;
  if (isbf) {
    a = *(const short8*)((const u16*)Av + (long)r * lda + k0 + q * 8);
#pragma unroll
    for (int j = 0; j < 8; j++) {
      if (((u16)a[j] & 0x7fffu) == 0)
        a[j] = (short)((const u16*)me)[k0 + q * 8 + j];
    }
  } else {
    const float* A = (const float*)Av;
    const uint4* p = (const uint4*)(A + (long)r * lda + k0 + q * 8);
    uint4 w0 = p[0];
    uint4 w1 = p[1];
    unsigned int ww[8] = {w0.x, w0.y, w0.z, w0.w, w1.x, w1.y, w1.z, w1.w};
#pragma unroll
    for (int j = 0; j < 8; j++) {
      if ((ww[j] & 0x7fffffffu) == 0)
        a[j] = (short)f2b(((const float*)me)[k0 + q * 8 + j]);
      else
        a[j] = (short)f2b(__builtin_bit_cast(float, ww[j]));
    }
  }
  return a;
}

// ------------- layer-1 GEMM, e/c split across blocks; B staged in LDS (k8-major):
// blocks [0,gb): tbuf[r][0:128]   = x' @ W1e  (K=256, B=64KB)
// blocks [gb,2gb): tbuf[r][128:256] = c' @ W1c  (K=128, B=32KB)
__global__ __launch_bounds__(256) void gemm_l1(
    const void* __restrict__ x, const void* __restrict__ cc,
    const void* __restrict__ mex, const void* __restrict__ mec,
    const u16* __restrict__ w1e_t, const u16* __restrict__ w1c_t,
    int M, int gb, u16* __restrict__ tb, const int* __restrict__ flagp) {
  __shared__ __align__(16) u16 bs[32768];  // 64 KB
  bool isbf = (*flagp != 0);
  bool isC = (blockIdx.x >= (unsigned)gb);
  int bid = isC ? (int)blockIdx.x - gb : (int)blockIdx.x;
  int tid = threadIdx.x;
  int wid = tid >> 6;
  int lane = tid & 63;
  int l15 = lane & 15;
  int q = lane >> 4;
  int row0 = bid * 64 + wid * 16;
  int r = row0 + l15;
  if (r >= M) r = M - 1;

  const void* A  = isC ? cc : x;
  const void* me = isC ? mec : mex;
  const u16* wt  = isC ? w1c_t : w1e_t;
  int K    = isC ? 128 : 256;
  int cofs = isC ? 128 : 0;

  // stage B: linear coalesced copy (wt already in [K/8][128][8] order)
  int nchunk = K * 16;  // (128*K)/8 16-byte chunks
  for (int i = tid; i < nchunk; i += 256)
    *(uint4*)(bs + i * 8) = *(const uint4*)(wt + i * 8);
  __syncthreads();

  floatx4 acc[8];
#pragma unroll
  for (int n = 0; n < 8; n++) acc[n] = (floatx4){0, 0, 0, 0};

  for (int k0 = 0; k0 < K; k0 += 32) {
    short8 a = load_a_me(A, K, me, r, k0, q, isbf);
    const u16* bb = bs + ((k0 >> 3) + q) * 1024 + l15 * 8;
#pragma unroll
    for (int n = 0; n < 8; n++) {
      short8 b = *(const short8*)(bb + n * 128);
      acc[n] = __builtin_amdgcn_mfma_f32_16x16x32_bf16(a, b, acc[n], 0, 0, 0);
    }
  }
#pragma unroll
  for (int n = 0; n < 8; n++)
#pragma unroll
    for (int rr = 0; rr < 4; rr++) {
      int row = row0 + q * 4 + rr;
      if (row < M) tb[(long)row * 256 + cofs + n * 16 + l15] = f2b(acc[n][rr]);
    }
}

// ------------- layer-2 GEMM, e/c split across blocks; B staged in LDS (k8-major, 32KB):
// reads row-major ubuf, writes row-major tbuf (for agg_head).
__global__ __launch_bounds__(256) void gemm_l2(
    const u16* __restrict__ u,
    const u16* __restrict__ w2e_t, const u16* __restrict__ w2c_t,
    int M, int gb, u16* __restrict__ tb) {
  __shared__ __align__(16) u16 bs[16384];  // 32 KB
  bool isC = (blockIdx.x >= (unsigned)gb);
  int bid = isC ? (int)blockIdx.x - gb : (int)blockIdx.x;
  int tid = threadIdx.x;
  int wid = tid >> 6;
  int lane = tid & 63;
  int l15 = lane & 15;
  int q = lane >> 4;
  int row0 = bid * 64 + wid * 16;
  int r = row0 + l15;
  if (r >= M) r = M - 1;

  const u16* wt = isC ? w2c_t : w2e_t;
  int aofs = isC ? 128 : 0;

  for (int i = tid; i < 2048; i += 256)
    *(uint4*)(bs + i * 8) = *(const uint4*)(wt + i * 8);
  __syncthreads();

  floatx4 acc[8];
#pragma unroll
  for (int n = 0; n < 8; n++) acc[n] = (floatx4){0, 0, 0, 0};

  for (int k0 = 0; k0 < 128; k0 += 32) {
    short8 a = *(const short8*)(u + (long)r * 256 + aofs + k0 + q * 8);
    const u16* bb = bs + ((k0 >> 3) + q) * 1024 + l15 * 8;
#pragma unroll
    for (int n = 0; n < 8; n++) {
      short8 b = *(const short8*)(bb + n * 128);
      acc[n] = __builtin_amdgcn_mfma_f32_16x16x32_bf16(a, b, acc[n], 0, 0, 0);
    }
  }
#pragma unroll
  for (int n = 0; n < 8; n++)
#pragma unroll
    for (int rr = 0; rr < 4; rr++) {
      int row = row0 + q * 4 + rr;
      if (row < M) tb[(long)row * 256 + aofs + n * 16 + l15] = f2b(acc[n][rr]);
    }
}

// ===== gather core: round-0 layout (64 lanes x uint2 = one coalesced 512B row/instr).
// Depth-8 software pipeline: 8 row-gathers in flight per wave; col indices via SCALAR
// loads (wave-uniform -> s_load, SGPR-resident, zero VGPR cost; no clamps thanks to the
// zero pad on colarr); ONE masked final batch (tail -> guaranteed-zero row).
__device__ __forceinline__ void gin_gather8(
    const u16* __restrict__ t, const int* __restrict__ rowptr,
    const int* __restrict__ colarr, const u16* __restrict__ zrow,
    int node, long fbB, floatx2& s01, floatx2& s23) {
  const char* base = (const char*)t + fbB;   // per-lane feature base
  const char* zb = (const char*)zrow + fbB;  // zero row
  s01 = (floatx2){0.f, 0.f};
  s23 = (floatx2){0.f, 0.f};
  int eu  = __builtin_amdgcn_readfirstlane(rowptr[node]);
  int e1u = __builtin_amdgcn_readfirstlane(rowptr[node + 1]);
  int c0 = colarr[eu],     c1 = colarr[eu + 1], c2 = colarr[eu + 2], c3 = colarr[eu + 3];
  int c4 = colarr[eu + 4], c5 = colarr[eu + 5], c6 = colarr[eu + 6], c7 = colarr[eu + 7];
  int eb = eu;
  for (; eb + 8 <= e1u; eb += 8) {
    uint2 w0 = *(const uint2*)(base + ((long)c0 << 9));
    uint2 w1 = *(const uint2*)(base + ((long)c1 << 9));
    uint2 w2 = *(const uint2*)(base + ((long)c2 << 9));
    uint2 w3 = *(const uint2*)(base + ((long)c3 << 9));
    uint2 w4 = *(const uint2*)(base + ((long)c4 << 9));
    uint2 w5 = *(const uint2*)(base + ((long)c5 << 9));
    uint2 w6 = *(const uint2*)(base + ((long)c6 << 9));
    uint2 w7 = *(const uint2*)(base + ((long)c7 << 9));
    int n0 = colarr[eb + 8],  n1 = colarr[eb + 9],  n2 = colarr[eb + 10], n3 = colarr[eb + 11];
    int n4 = colarr[eb + 12], n5 = colarr[eb + 13], n6 = colarr[eb + 14], n7 = colarr[eb + 15];
    s01 += up2(w0.x); s23 += up2(w0.y);
    s01 += up2(w1.x); s23 += up2(w1.y);
    s01 += up2(w2.x); s23 += up2(w2.y);
    s01 += up2(w3.x); s23 += up2(w3.y);
    s01 += up2(w4.x); s23 += up2(w4.y);
    s01 += up2(w5.x); s23 += up2(w5.y);
    s01 += up2(w6.x); s23 += up2(w6.y);
    s01 += up2(w7.x); s23 += up2(w7.y);
    c0 = n0; c1 = n1; c2 = n2; c3 = n3;
    c4 = n4; c5 = n5; c6 = n6; c7 = n7;
  }
  int rem = e1u - eb;  // 0..7
  if (rem > 0) {
    const char* p0 = base + ((long)c0 << 9);
    const char* p1 = (1 < rem) ? base + ((long)c1 << 9) : zb;
    const char* p2 = (2 < rem) ? base + ((long)c2 << 9) : zb;
    const char* p3 = (3 < rem) ? base + ((long)c3 << 9) : zb;
    const char* p4 = (4 < rem) ? base + ((long)c4 << 9) : zb;
    const char* p5 = (5 < rem) ? base + ((long)c5 << 9) : zb;
    const char* p6 = (6 < rem) ? base + ((long)c6 << 9) : zb;
    const char* p7 = (7 < rem) ? base + ((long)c7 << 9) : zb;
    uint2 w0 = *(const uint2*)p0;
    uint2 w1 = *(const uint2*)p1;
    uint2 w2 = *(const uint2*)p2;
    uint2 w3 = *(const uint2*)p3;
    uint2 w4 = *(const uint2*)p4;
    uint2 w5 = *(const uint2*)p5;
    uint2 w6 = *(const uint2*)p6;
    uint2 w7 = *(const uint2*)p7;
    s01 += up2(w0.x); s23 += up2(w0.y);
    s01 += up2(w1.x); s23 += up2(w1.y);
    s01 += up2(w2.x); s23 += up2(w2.y);
    s01 += up2(w3.x); s23 += up2(w3.y);
    s01 += up2(w4.x); s23 += up2(w4.y);
    s01 += up2(w5.x); s23 += up2(w5.y);
    s01 += up2(w6.x); s23 += up2(w6.y);
    s01 += up2(w7.x); s23 += up2(w7.y);
  }
}

// ------- agg layer-1 (wave per node, 4 feats/lane; bf16 out) -------
__global__ __launch_bounds__(256) void agg_kernel(
    const u16* __restrict__ t, const int* __restrict__ rowptr, const int* __restrict__ colarr,
    const void* __restrict__ epsE, const void* __restrict__ epsC,
    const void* __restrict__ bE, const void* __restrict__ bC,
    u16* __restrict__ u, int N, const u16* __restrict__ zrow,
    const int* __restrict__ flagp) {
  int node = blockIdx.x * 4 + __builtin_amdgcn_readfirstlane(threadIdx.x >> 6);
  if (node >= N) return;
  bool isbf = (*flagp != 0);
  int lane = threadIdx.x & 63;
  int f0 = lane << 2;
  long fbB = (long)f0 << 1;  // lane*8 bytes
  const u16* tb = t + f0;

  uint2 ps = *(const uint2*)(tb + ((long)node << 8));  // self row, issued early

  floatx2 s01, s23;
  gin_gather8(t, rowptr, colarr, zrow, node, fbB, s01, s23);

  bool isE = (lane < 32);
  float eps2 = 2.0f + rdf(isbf, isE ? epsE : epsC, 0);
  const void* bp = isE ? bE : bC;
  int bi = isE ? f0 : (f0 - 128);
  float a0 = lrelu(s01.x + eps2 * lo2f(ps.x) + rdf(isbf, bp, bi + 0));
  float a1 = lrelu(s01.y + eps2 * hi2f(ps.x) + rdf(isbf, bp, bi + 1));
  float a2 = lrelu(s23.x + eps2 * lo2f(ps.y) + rdf(isbf, bp, bi + 2));
  float a3 = lrelu(s23.y + eps2 * hi2f(ps.y) + rdf(isbf, bp, bi + 3));
  uint2 o;
  o.x = ((unsigned int)f2b(a1) << 16) | f2b(a0);
  o.y = ((unsigned int)f2b(a3) << 16) | f2b(a2);
  *(uint2*)(u + ((long)node << 8) + f0) = o;
}

// ------- agg layer-2 + head fused: out[node] = lrelu(u @ Wm + bm) -------
__global__ __launch_bounds__(256) void agg_head(
    const u16* __restrict__ t, const int* __restrict__ rowptr, const int* __restrict__ colarr,
    const void* __restrict__ epsE, const void* __restrict__ epsC,
    const void* __restrict__ bE, const void* __restrict__ bC,
    const u16* __restrict__ wm_t, const void* __restrict__ bm,
    float* __restrict__ out, int N, const u16* __restrict__ zrow,
    const int* __restrict__ flagp) {
  __shared__ float wmf[2048];  // [col][f] f32, from wm_t [16][256] (cols 0..7)
  __shared__ float bmf[8];
  bool isbf = (*flagp != 0);
  int tid = threadIdx.x;
  for (int i = tid; i < 2048; i += 256) wmf[i] = b2f((unsigned int)wm_t[i]);
  if (tid < 8) bmf[tid] = rdf(isbf, bm, tid);
  __syncthreads();

  int node = blockIdx.x * 4 + __builtin_amdgcn_readfirstlane(tid >> 6);
  if (node >= N) return;
  int lane = tid & 63;
  int f0 = lane << 2;
  long fbB = (long)f0 << 1;
  const u16* tb = t + f0;

  uint2 ps = *(const uint2*)(tb + ((long)node << 8));  // self row, issued early

  floatx2 s01, s23;
  gin_gather8(t, rowptr, colarr, zrow, node, fbB, s01, s23);

  bool isE = (lane < 32);
  float eps2 = 2.0f + rdf(isbf, isE ? epsE : epsC, 0);
  const void* bp = isE ? bE : bC;
  int bi = isE ? f0 : (f0 - 128);
  float a0 = lrelu(s01.x + eps2 * lo2f(ps.x) + rdf(isbf, bp, bi + 0));
  float a1 = lrelu(s01.y + eps2 * hi2f(ps.x) + rdf(isbf, bp, bi + 1));
  float a2 = lrelu(s23.x + eps2 * lo2f(ps.y) + rdf(isbf, bp, bi + 2));
  float a3 = lrelu(s23.y + eps2 * hi2f(ps.y) + rdf(isbf, bp, bi + 3));

  // head: p[col] = sum_f u[f] * Wm[f][col]  (per-lane 4-feat partial, then 64-lane butterfly)
  float p[8];
#pragma unroll
  for (int col = 0; col < 8; col++) {
    float4 w = *(const float4*)&wmf[col * 256 + f0];
    p[col] = a0 * w.x + a1 * w.y + a2 * w.z + a3 * w.w;
  }
#pragma unroll
  for (int m = 1; m < 64; m <<= 1) {
#pragma unroll
    for (int col = 0; col < 8; col++) p[col] += __shfl_xor(p[col], m, 64);
  }
  if (lane == 0) {
    float4 o0, o1;
    o0.x = lrelu(p[0] + bmf[0]); o0.y = lrelu(p[1] + bmf[1]);
    o0.z = lrelu(p[2] + bmf[2]); o0.w = lrelu(p[3] + bmf[3]);
    o1.x = lrelu(p[4] + bmf[4]); o1.y = lrelu(p[5] + bmf[5]);
    o1.z = lrelu(p[6] + bmf[6]); o1.w = lrelu(p[7] + bmf[7]);
    *(float4*)(out + (long)node * 8) = o0;
    *(float4*)(out + (long)node * 8 + 4) = o1;
  }
}

// ---------------- central-node MLP (f32 in, f32 out) ----------------
__global__ __launch_bounds__(128) void mlp_kernel(
    const float* __restrict__ outbuf, const int* __restrict__ central,
    const void* __restrict__ Wp1, const void* __restrict__ bp1,
    const void* __restrict__ Wp2, const void* __restrict__ bp2,
    float* __restrict__ logits, const int* __restrict__ flagp) {
  __shared__ float h1[128];
  __shared__ float o[8];
  bool isbf = (*flagp != 0);
  int b = blockIdx.x, tid = threadIdx.x;
  int node = central[b];
  if (tid < 8) o[tid] = outbuf[node * 8 + tid];
  __syncthreads();
  float s = rdf(isbf, bp1, tid);
#pragma unroll
  for (int k = 0; k < 8; k++) s += o[k] * rdf(isbf, Wp1, k * 128 + tid);
  h1[tid] = fmaxf(s, 0.f);
  __syncthreads();
  if (tid < 8) {
    float s2 = rdf(isbf, bp2, tid);
    for (int k = 0; k < 128; k++) s2 += h1[k] * rdf(isbf, Wp2, k * 8 + tid);
    logits[b * 8 + tid] = s2;
  }
}

extern "C" void kernel_launch(void* const* d_in, const int* in_sizes, int n_in,
                              void* d_out, int out_size, void* d_ws, size_t ws_size,
                              hipStream_t stream) {
  const void* x    = d_in[0];
  const void* c    = d_in[1];
  const int* eidx  = (const int*)d_in[2];
  const int* cidx  = (const int*)d_in[3];
  const void* me_x = d_in[4];
  const void* me_c = d_in[5];
  const void* W1e  = d_in[6];
  const void* b1e  = d_in[7];
  const void* e1e  = d_in[8];
  const void* W2e  = d_in[9];
  const void* b2e  = d_in[10];
  const void* e2e  = d_in[11];
  const void* W1c  = d_in[12];
  const void* b1c  = d_in[13];
  const void* e1c  = d_in[14];
  const void* W2c  = d_in[15];
  const void* b2c  = d_in[16];
  const void* e2c  = d_in[17];
  const void* Wm   = d_in[18];
  const void* bm   = d_in[19];
  const void* Wp1  = d_in[20];
  const void* bp1  = d_in[21];
  const void* Wp2  = d_in[22];
  const void* bp2  = d_in[23];

  const int N = in_sizes[0] / 256;   // 50000
  const int E = in_sizes[2] / 2;     // 800000
  const int Cn = in_sizes[3];        // 512
  const int* src = eidx;
  const int* dst = eidx + E;

  char* ws = (char*)d_ws;
  int* deg    = (int*)(ws + 0);          // 200000 B
  int* rowptr = (int*)(ws + 200192);     // 200004 B
  int* cursor = (int*)(ws + 400384);     // 200000 B
  int* colarr = (int*)(ws + 600576);     // 3200000 B + 192 B zero pad
  u16* tbuf   = (u16*)(ws + 3800832);    // 25600000 B  [N,256] bf16
  u16* ubuf   = (u16*)(ws + 29400832);   // 25600000 B  [N,256] bf16
  u16* wt_all = (u16*)(ws + 55000832);   // 172032 B
  int* flag   = (int*)(ws + 55172864);   // 4 B
  int* bsum   = (int*)(ws + 55173120);   // 256 B
  int* boff   = (int*)(ws + 55173376);   // 256 B

  u16* w1e_t = wt_all + 0;       // [32][128][8]  k8-major, 64 KB
  u16* w1c_t = wt_all + 32768;   // [16][128][8]  k8-major, 32 KB
  u16* w2e_t = wt_all + 49152;   // [16][128][8]
  u16* w2c_t = wt_all + 65536;   // [16][128][8]
  u16* wm_t  = wt_all + 81920;   // [16][256]  (rows 8..15 are zeros)
  const u16* zrow = wt_all + 83968;  // = wm_t + 8*256: guaranteed-zero 512 B row

  // init: zero deg + colarr pad (48 entries) + dtype detect
  init_kernel<<<(N + 1023) / 1024, 256, 0, stream>>>(deg, N, (const u16*)x, flag,
                                                     colarr, E);

  // CSR build
  hist_kernel<<<(E + 255) / 256, 256, 0, stream>>>(dst, E, deg);
  int PB = (N + SCB - 1) / SCB;  // 49
  scan_phaseA<<<PB, 256, 0, stream>>>(deg, bsum, N);
  scan_phaseB<<<1, 64, 0, stream>>>(bsum, boff, PB, rowptr, N);
  scan_phaseC<<<PB, 256, 0, stream>>>(deg, boff, rowptr, cursor, N);
  fill_kernel<<<(E + 255) / 256, 256, 0, stream>>>(src, dst, E, cursor, colarr);

  // weight transposes
  TWDesc td;
  td.W[0] = W1e; td.K[0] = 256; td.Nc[0] = 128;
  td.W[1] = W1c; td.K[1] = 128; td.Nc[1] = 128;
  td.W[2] = W2e; td.K[2] = 128; td.Nc[2] = 128;
  td.W[3] = W2c; td.K[3] = 128; td.Nc[3] = 128;
  td.W[4] = Wm;  td.K[4] = 256; td.Nc[4] = 8;
  td.base[0] = 0; td.base[1] = 32768; td.base[2] = 49152;
  td.base[3] = 65536; td.base[4] = 81920; td.base[5] = 86016;
  transpose_all<<<(86016 + 255) / 256, 256, 0, stream>>>(td, wt_all, flag);

  int gb = (N + 63) / 64;  // 782
  // layer 1 (e/c split; LDS-staged B)
  gemm_l1<<<2 * gb, 256, 0, stream>>>(x, c, me_x, me_c, w1e_t, w1c_t, N, gb, tbuf, flag);
  agg_kernel<<<(N + 3) / 4, 256, 0, stream>>>(tbuf, rowptr, colarr,
      e1e, e1c, b1e, b1c, ubuf, N, zrow, flag);
  // layer 2 (e/c split; LDS-staged B)
  gemm_l2<<<2 * gb, 256, 0, stream>>>(ubuf, w2e_t, w2c_t, N, gb, tbuf);
  // agg2 + head fused -> d_out[0 : N*8] f32
  agg_head<<<(N + 3) / 4, 256, 0, stream>>>(tbuf, rowptr, colarr,
      e2e, e2c, b2e, b2c, wm_t, bm, (float*)d_out, N, zrow, flag);
  // central MLP -> d_out[N*8 : ...]
  mlp_kernel<<<Cn, 128, 0, stream>>>((const float*)d_out, cidx,
      Wp1, bp1, Wp2, bp2, (float*)d_out + (size_t)N * 8, flag);
}

// Round 12
// 396.742 us; speedup vs baseline: 1.2623x; 1.0468x over previous
//
#include <hip/hip_runtime.h>

typedef unsigned short u16;
typedef __attribute__((ext_vector_type(8))) short short8;
typedef __attribute__((ext_vector_type(4))) float floatx4;
typedef __attribute__((ext_vector_type(2))) float floatx2;

__device__ __forceinline__ float b2f(unsigned int ubits) {
  union { unsigned int i; float f; } cv; cv.i = ubits << 16; return cv.f;
}
__device__ __forceinline__ float hi2f(unsigned int u) {
  union { unsigned int i; float f; } cv; cv.i = u & 0xffff0000u; return cv.f;
}
__device__ __forceinline__ float lo2f(unsigned int u) {
  union { unsigned int i; float f; } cv; cv.i = u << 16; return cv.f;
}
__device__ __forceinline__ u16 f2b(float f) {
  unsigned int u = __builtin_bit_cast(unsigned int, f);
  u += 0x7fffu + ((u >> 16) & 1u);   // RNE
  return (u16)(u >> 16);
}
__device__ __forceinline__ float lrelu(float v) { return v > 0.f ? v : 0.2f * v; }
__device__ __forceinline__ float rdf(bool isbf, const void* p, int idx) {
  return isbf ? b2f((unsigned int)((const u16*)p)[idx]) : ((const float*)p)[idx];
}
__device__ __forceinline__ floatx2 up2(unsigned int u) {
  return (floatx2){lo2f(u), hi2f(u)};   // (even feat, odd feat) -> v_pk_add_f32
}

// ---------------- init: zero deg + colarr pad (48) + dtype detect (block 0) ----------------
__global__ __launch_bounds__(256) void init_kernel(int* __restrict__ deg, int n,
                                                   const u16* __restrict__ probe,
                                                   int* __restrict__ flag,
                                                   int* __restrict__ colarr, int E) {
  int i0 = (blockIdx.x * 256 + threadIdx.x) * 4;
  if (i0 + 3 < n) {
    *(int4*)(deg + i0) = make_int4(0, 0, 0, 0);
  } else {
    for (int j = 0; j < 4; j++) if (i0 + j < n) deg[i0 + j] = 0;
  }
  if (blockIdx.x == 0) {
    if (threadIdx.x >= 64 && threadIdx.x < 112) colarr[E + (int)threadIdx.x - 64] = 0;
    if (threadIdx.x < 64) {
      int lane = threadIdx.x;
      int cnt = 0;
      for (int i = lane; i < 256; i += 64) {
        unsigned int u = probe[i];
        unsigned int e = (u >> 7) & 0xFFu;
        if ((u & 0x7fffu) == 0 || (e >= 60 && e <= 191)) cnt++;
      }
#pragma unroll
      for (int off = 32; off; off >>= 1) cnt += __shfl_down(cnt, off, 64);
      if (lane == 0) *flag = (cnt >= 240) ? 1 : 0;
    }
  }
}

// ---------------- CSR build ----------------
__global__ __launch_bounds__(256) void hist_kernel(const int* __restrict__ dst, int E,
                                                   int* __restrict__ deg) {
  int i = blockIdx.x * 256 + threadIdx.x;
  if (i < E) atomicAdd(deg + dst[i], 1);
}

#define SCB 1024  // nodes per scan block (256 thr x 4)

__global__ __launch_bounds__(256) void scan_phaseA(const int* __restrict__ deg,
                                                   int* __restrict__ bsum, int n) {
  int i0 = blockIdx.x * SCB + threadIdx.x * 4;
  int s = 0;
  if (i0 + 3 < n) {
    int4 v = *(const int4*)(deg + i0);
    s = v.x + v.y + v.z + v.w;
  } else {
    for (int j = 0; j < 4; j++) if (i0 + j < n) s += deg[i0 + j];
  }
#pragma unroll
  for (int off = 32; off; off >>= 1) s += __shfl_down(s, off, 64);
  __shared__ int ws4[4];
  int lane = threadIdx.x & 63, wid = threadIdx.x >> 6;
  if (lane == 0) ws4[wid] = s;
  __syncthreads();
  if (threadIdx.x == 0) bsum[blockIdx.x] = ws4[0] + ws4[1] + ws4[2] + ws4[3];
}

__global__ void scan_phaseB(const int* __restrict__ bsum, int* __restrict__ boff,
                            int PB, int* __restrict__ rowptr, int n) {
  int lane = threadIdx.x;  // 64, PB <= 64
  int v = (lane < PB) ? bsum[lane] : 0;
  int incl = v;
#pragma unroll
  for (int off = 1; off < 64; off <<= 1) {
    int t = __shfl_up(incl, off, 64);
    if (lane >= off) incl += t;
  }
  if (lane < PB) boff[lane] = incl - v;
  if (lane == 63) rowptr[n] = incl;
}

__global__ __launch_bounds__(256) void scan_phaseC(const int* __restrict__ deg,
                                                   const int* __restrict__ boff,
                                                   int* __restrict__ rowptr,
                                                   int* __restrict__ cursor, int n) {
  int i0 = blockIdx.x * SCB + threadIdx.x * 4;
  int v0 = 0, v1 = 0, v2 = 0, v3 = 0;
  if (i0 + 3 < n) {
    int4 v = *(const int4*)(deg + i0);
    v0 = v.x; v1 = v.y; v2 = v.z; v3 = v.w;
  } else {
    if (i0 < n) v0 = deg[i0];
    if (i0 + 1 < n) v1 = deg[i0 + 1];
    if (i0 + 2 < n) v2 = deg[i0 + 2];
    if (i0 + 3 < n) v3 = deg[i0 + 3];
  }
  int local = v0 + v1 + v2 + v3;
  int lane = threadIdx.x & 63, wid = threadIdx.x >> 6;
  int incl = local;
#pragma unroll
  for (int off = 1; off < 64; off <<= 1) {
    int t = __shfl_up(incl, off, 64);
    if (lane >= off) incl += t;
  }
  __shared__ int ws4[4];
  if (lane == 63) ws4[wid] = incl;
  __syncthreads();
  int woff = 0;
  for (int w = 0; w < wid; w++) woff += ws4[w];
  int run = boff[blockIdx.x] + woff + incl - local;
  if (i0 < n)     { rowptr[i0] = run;     cursor[i0] = run; }     run += v0;
  if (i0 + 1 < n) { rowptr[i0 + 1] = run; cursor[i0 + 1] = run; } run += v1;
  if (i0 + 2 < n) { rowptr[i0 + 2] = run; cursor[i0 + 2] = run; } run += v2;
  if (i0 + 3 < n) { rowptr[i0 + 3] = run; cursor[i0 + 3] = run; }
}

__global__ __launch_bounds__(256) void fill_kernel(const int* __restrict__ src,
                                                   const int* __restrict__ dst, int E,
                                                   int* __restrict__ cursor,
                                                   int* __restrict__ colarr) {
  int i = blockIdx.x * 256 + threadIdx.x;
  if (i < E) {
    int p = atomicAdd(cursor + dst[i], 1);
    colarr[p] = src[i];
  }
}

// -------- all weight transposes in one kernel ----------------------------------------
// segments 0..3 (GEMM B operands): k8-major layout  [K/8][128][8]
// segment 4 (Wm for agg_head): [16][256], rows 8..15 zero (zrow lives there).
struct TWDesc {
  const void* W[5];
  int K[5];
  int Nc[5];
  int base[6];  // u16 offsets
};

__global__ __launch_bounds__(256) void transpose_all(TWDesc d, u16* __restrict__ out,
                                                     const int* __restrict__ flagp) {
  bool isbf = (*flagp != 0);
  int idx = blockIdx.x * 256 + threadIdx.x;
  if (idx >= d.base[5]) return;
  int s = 0;
  while (idx >= d.base[s + 1]) s++;
  int local = idx - d.base[s];
  if (s < 4) {
    int k8 = local >> 10;          // local / (128*8)
    int rem = local & 1023;
    int col = rem >> 3;
    int k7 = rem & 7;
    int k = k8 * 8 + k7;
    out[idx] = f2b(rdf(isbf, d.W[s], k * 128 + col));   // Nc = 128 for all four
  } else {
    int nn = local >> 8;           // local / 256
    int k = local & 255;
    out[idx] = (nn < d.Nc[4]) ? f2b(rdf(isbf, d.W[4], k * d.Nc[4] + nn)) : (u16)0;
  }
}

// ---------------- A-fragment load (runtime dtype, exact-zero -> me) ----------------
__device__ __forceinline__ short8 load_a_me(const void* Av, int lda, const void* me,
                                            int r, int k0, int q, bool isbf) {
  short8 a;
  if (isbf) {
    a = *(const short8*)((const u16*)Av + (long)r * lda + k0 + q * 8);
#pragma unroll
    for (int j = 0; j < 8; j++) {
      if (((u16)a[j] & 0x7fffu) == 0)
        a[j] = (short)((const u16*)me)[k0 + q * 8 + j];
    }
  } else {
    const float* A = (const float*)Av;
    const uint4* p = (const uint4*)(A + (long)r * lda + k0 + q * 8);
    uint4 w0 = p[0];
    uint4 w1 = p[1];
    unsigned int ww[8] = {w0.x, w0.y, w0.z, w0.w, w1.x, w1.y, w1.z, w1.w};
#pragma unroll
    for (int j = 0; j < 8; j++) {
      if ((ww[j] & 0x7fffffffu) == 0)
        a[j] = (short)f2b(((const float*)me)[k0 + q * 8 + j]);
      else
        a[j] = (short)f2b(__builtin_bit_cast(float, ww[j]));
    }
  }
  return a;
}

// ------------- layer-1 GEMM, e/c split across blocks; B staged in LDS in 32KB
// K-chunks (K=128 per stage) -> 5 blocks/CU for BOTH halves (was 2 for e-half):
// blocks [0,gb): tbuf[r][0:128]   = x' @ W1e  (K=256, two stages)
// blocks [gb,2gb): tbuf[r][128:256] = c' @ W1c  (K=128, one stage)
__global__ __launch_bounds__(256) void gemm_l1(
    const void* __restrict__ x, const void* __restrict__ cc,
    const void* __restrict__ mex, const void* __restrict__ mec,
    const u16* __restrict__ w1e_t, const u16* __restrict__ w1c_t,
    int M, int gb, u16* __restrict__ tb, const int* __restrict__ flagp) {
  __shared__ __align__(16) u16 bs[16384];  // 32 KB
  bool isbf = (*flagp != 0);
  bool isC = (blockIdx.x >= (unsigned)gb);
  int bid = isC ? (int)blockIdx.x - gb : (int)blockIdx.x;
  int tid = threadIdx.x;
  int wid = tid >> 6;
  int lane = tid & 63;
  int l15 = lane & 15;
  int q = lane >> 4;
  int row0 = bid * 64 + wid * 16;
  int r = row0 + l15;
  if (r >= M) r = M - 1;

  const void* A  = isC ? cc : x;
  const void* me = isC ? mec : mex;
  const u16* wt  = isC ? w1c_t : w1e_t;
  int K    = isC ? 128 : 256;
  int cofs = isC ? 128 : 0;

  floatx4 acc[8];
#pragma unroll
  for (int n = 0; n < 8; n++) acc[n] = (floatx4){0, 0, 0, 0};

  for (int kt = 0; kt < K; kt += 128) {
    // stage B chunk [kt, kt+128): contiguous 32 KB in k8-major layout
    const u16* wsrc = wt + (kt >> 3) * 1024;
    for (int i = tid; i < 2048; i += 256)
      *(uint4*)(bs + i * 8) = *(const uint4*)(wsrc + i * 8);
    __syncthreads();

    for (int k0 = 0; k0 < 128; k0 += 32) {
      short8 a = load_a_me(A, K, me, r, kt + k0, q, isbf);
      const u16* bb = bs + ((k0 >> 3) + q) * 1024 + l15 * 8;
#pragma unroll
      for (int n = 0; n < 8; n++) {
        short8 b = *(const short8*)(bb + n * 128);
        acc[n] = __builtin_amdgcn_mfma_f32_16x16x32_bf16(a, b, acc[n], 0, 0, 0);
      }
    }
    __syncthreads();  // protect bs before next-chunk overwrite
  }
#pragma unroll
  for (int n = 0; n < 8; n++)
#pragma unroll
    for (int rr = 0; rr < 4; rr++) {
      int row = row0 + q * 4 + rr;
      if (row < M) tb[(long)row * 256 + cofs + n * 16 + l15] = f2b(acc[n][rr]);
    }
}

// ------------- layer-2 GEMM, e/c split across blocks; B staged in LDS (k8-major, 32KB):
// reads row-major ubuf, writes row-major tbuf (for agg_head).
__global__ __launch_bounds__(256) void gemm_l2(
    const u16* __restrict__ u,
    const u16* __restrict__ w2e_t, const u16* __restrict__ w2c_t,
    int M, int gb, u16* __restrict__ tb) {
  __shared__ __align__(16) u16 bs[16384];  // 32 KB
  bool isC = (blockIdx.x >= (unsigned)gb);
  int bid = isC ? (int)blockIdx.x - gb : (int)blockIdx.x;
  int tid = threadIdx.x;
  int wid = tid >> 6;
  int lane = tid & 63;
  int l15 = lane & 15;
  int q = lane >> 4;
  int row0 = bid * 64 + wid * 16;
  int r = row0 + l15;
  if (r >= M) r = M - 1;

  const u16* wt = isC ? w2c_t : w2e_t;
  int aofs = isC ? 128 : 0;

  for (int i = tid; i < 2048; i += 256)
    *(uint4*)(bs + i * 8) = *(const uint4*)(wt + i * 8);
  __syncthreads();

  floatx4 acc[8];
#pragma unroll
  for (int n = 0; n < 8; n++) acc[n] = (floatx4){0, 0, 0, 0};

  for (int k0 = 0; k0 < 128; k0 += 32) {
    short8 a = *(const short8*)(u + (long)r * 256 + aofs + k0 + q * 8);
    const u16* bb = bs + ((k0 >> 3) + q) * 1024 + l15 * 8;
#pragma unroll
    for (int n = 0; n < 8; n++) {
      short8 b = *(const short8*)(bb + n * 128);
      acc[n] = __builtin_amdgcn_mfma_f32_16x16x32_bf16(a, b, acc[n], 0, 0, 0);
    }
  }
#pragma unroll
  for (int n = 0; n < 8; n++)
#pragma unroll
    for (int rr = 0; rr < 4; rr++) {
      int row = row0 + q * 4 + rr;
      if (row < M) tb[(long)row * 256 + aofs + n * 16 + l15] = f2b(acc[n][rr]);
    }
}

// ===== gather core: round-0 layout (64 lanes x uint2 = one coalesced 512B row/instr).
// Depth-8 software pipeline: 8 row-gathers in flight per wave; col indices via SCALAR
// loads (wave-uniform -> s_load, SGPR-resident, zero VGPR cost; no clamps thanks to the
// zero pad on colarr); ONE masked final batch (tail -> guaranteed-zero row).
__device__ __forceinline__ void gin_gather8(
    const u16* __restrict__ t, const int* __restrict__ rowptr,
    const int* __restrict__ colarr, const u16* __restrict__ zrow,
    int node, long fbB, floatx2& s01, floatx2& s23) {
  const char* base = (const char*)t + fbB;   // per-lane feature base
  const char* zb = (const char*)zrow + fbB;  // zero row
  s01 = (floatx2){0.f, 0.f};
  s23 = (floatx2){0.f, 0.f};
  int eu  = __builtin_amdgcn_readfirstlane(rowptr[node]);
  int e1u = __builtin_amdgcn_readfirstlane(rowptr[node + 1]);
  int c0 = colarr[eu],     c1 = colarr[eu + 1], c2 = colarr[eu + 2], c3 = colarr[eu + 3];
  int c4 = colarr[eu + 4], c5 = colarr[eu + 5], c6 = colarr[eu + 6], c7 = colarr[eu + 7];
  int eb = eu;
  for (; eb + 8 <= e1u; eb += 8) {
    uint2 w0 = *(const uint2*)(base + ((long)c0 << 9));
    uint2 w1 = *(const uint2*)(base + ((long)c1 << 9));
    uint2 w2 = *(const uint2*)(base + ((long)c2 << 9));
    uint2 w3 = *(const uint2*)(base + ((long)c3 << 9));
    uint2 w4 = *(const uint2*)(base + ((long)c4 << 9));
    uint2 w5 = *(const uint2*)(base + ((long)c5 << 9));
    uint2 w6 = *(const uint2*)(base + ((long)c6 << 9));
    uint2 w7 = *(const uint2*)(base + ((long)c7 << 9));
    int n0 = colarr[eb + 8],  n1 = colarr[eb + 9],  n2 = colarr[eb + 10], n3 = colarr[eb + 11];
    int n4 = colarr[eb + 12], n5 = colarr[eb + 13], n6 = colarr[eb + 14], n7 = colarr[eb + 15];
    s01 += up2(w0.x); s23 += up2(w0.y);
    s01 += up2(w1.x); s23 += up2(w1.y);
    s01 += up2(w2.x); s23 += up2(w2.y);
    s01 += up2(w3.x); s23 += up2(w3.y);
    s01 += up2(w4.x); s23 += up2(w4.y);
    s01 += up2(w5.x); s23 += up2(w5.y);
    s01 += up2(w6.x); s23 += up2(w6.y);
    s01 += up2(w7.x); s23 += up2(w7.y);
    c0 = n0; c1 = n1; c2 = n2; c3 = n3;
    c4 = n4; c5 = n5; c6 = n6; c7 = n7;
  }
  int rem = e1u - eb;  // 0..7
  if (rem > 0) {
    const char* p0 = base + ((long)c0 << 9);
    const char* p1 = (1 < rem) ? base + ((long)c1 << 9) : zb;
    const char* p2 = (2 < rem) ? base + ((long)c2 << 9) : zb;
    const char* p3 = (3 < rem) ? base + ((long)c3 << 9) : zb;
    const char* p4 = (4 < rem) ? base + ((long)c4 << 9) : zb;
    const char* p5 = (5 < rem) ? base + ((long)c5 << 9) : zb;
    const char* p6 = (6 < rem) ? base + ((long)c6 << 9) : zb;
    const char* p7 = (7 < rem) ? base + ((long)c7 << 9) : zb;
    uint2 w0 = *(const uint2*)p0;
    uint2 w1 = *(const uint2*)p1;
    uint2 w2 = *(const uint2*)p2;
    uint2 w3 = *(const uint2*)p3;
    uint2 w4 = *(const uint2*)p4;
    uint2 w5 = *(const uint2*)p5;
    uint2 w6 = *(const uint2*)p6;
    uint2 w7 = *(const uint2*)p7;
    s01 += up2(w0.x); s23 += up2(w0.y);
    s01 += up2(w1.x); s23 += up2(w1.y);
    s01 += up2(w2.x); s23 += up2(w2.y);
    s01 += up2(w3.x); s23 += up2(w3.y);
    s01 += up2(w4.x); s23 += up2(w4.y);
    s01 += up2(w5.x); s23 += up2(w5.y);
    s01 += up2(w6.x); s23 += up2(w6.y);
    s01 += up2(w7.x); s23 += up2(w7.y);
  }
}

// ------- agg layer-1 (wave per node, 4 feats/lane; bf16 out) -------
__global__ __launch_bounds__(256) void agg_kernel(
    const u16* __restrict__ t, const int* __restrict__ rowptr, const int* __restrict__ colarr,
    const void* __restrict__ epsE, const void* __restrict__ epsC,
    const void* __restrict__ bE, const void* __restrict__ bC,
    u16* __restrict__ u, int N, const u16* __restrict__ zrow,
    const int* __restrict__ flagp) {
  int node = blockIdx.x * 4 + __builtin_amdgcn_readfirstlane(threadIdx.x >> 6);
  if (node >= N) return;
  bool isbf = (*flagp != 0);
  int lane = threadIdx.x & 63;
  int f0 = lane << 2;
  long fbB = (long)f0 << 1;  // lane*8 bytes
  const u16* tb = t + f0;

  uint2 ps = *(const uint2*)(tb + ((long)node << 8));  // self row, issued early

  floatx2 s01, s23;
  gin_gather8(t, rowptr, colarr, zrow, node, fbB, s01, s23);

  bool isE = (lane < 32);
  float eps2 = 2.0f + rdf(isbf, isE ? epsE : epsC, 0);
  const void* bp = isE ? bE : bC;
  int bi = isE ? f0 : (f0 - 128);
  float a0 = lrelu(s01.x + eps2 * lo2f(ps.x) + rdf(isbf, bp, bi + 0));
  float a1 = lrelu(s01.y + eps2 * hi2f(ps.x) + rdf(isbf, bp, bi + 1));
  float a2 = lrelu(s23.x + eps2 * lo2f(ps.y) + rdf(isbf, bp, bi + 2));
  float a3 = lrelu(s23.y + eps2 * hi2f(ps.y) + rdf(isbf, bp, bi + 3));
  uint2 o;
  o.x = ((unsigned int)f2b(a1) << 16) | f2b(a0);
  o.y = ((unsigned int)f2b(a3) << 16) | f2b(a2);
  *(uint2*)(u + ((long)node << 8) + f0) = o;
}

// ------- agg layer-2 + head fused: out[node] = lrelu(u @ Wm + bm) -------
__global__ __launch_bounds__(256) void agg_head(
    const u16* __restrict__ t, const int* __restrict__ rowptr, const int* __restrict__ colarr,
    const void* __restrict__ epsE, const void* __restrict__ epsC,
    const void* __restrict__ bE, const void* __restrict__ bC,
    const u16* __restrict__ wm_t, const void* __restrict__ bm,
    float* __restrict__ out, int N, const u16* __restrict__ zrow,
    const int* __restrict__ flagp) {
  __shared__ float wmf[2048];  // [col][f] f32, from wm_t [16][256] (cols 0..7)
  __shared__ float bmf[8];
  bool isbf = (*flagp != 0);
  int tid = threadIdx.x;
  for (int i = tid; i < 2048; i += 256) wmf[i] = b2f((unsigned int)wm_t[i]);
  if (tid < 8) bmf[tid] = rdf(isbf, bm, tid);
  __syncthreads();

  int node = blockIdx.x * 4 + __builtin_amdgcn_readfirstlane(tid >> 6);
  if (node >= N) return;
  int lane = tid & 63;
  int f0 = lane << 2;
  long fbB = (long)f0 << 1;
  const u16* tb = t + f0;

  uint2 ps = *(const uint2*)(tb + ((long)node << 8));  // self row, issued early

  floatx2 s01, s23;
  gin_gather8(t, rowptr, colarr, zrow, node, fbB, s01, s23);

  bool isE = (lane < 32);
  float eps2 = 2.0f + rdf(isbf, isE ? epsE : epsC, 0);
  const void* bp = isE ? bE : bC;
  int bi = isE ? f0 : (f0 - 128);
  float a0 = lrelu(s01.x + eps2 * lo2f(ps.x) + rdf(isbf, bp, bi + 0));
  float a1 = lrelu(s01.y + eps2 * hi2f(ps.x) + rdf(isbf, bp, bi + 1));
  float a2 = lrelu(s23.x + eps2 * lo2f(ps.y) + rdf(isbf, bp, bi + 2));
  float a3 = lrelu(s23.y + eps2 * hi2f(ps.y) + rdf(isbf, bp, bi + 3));

  // head: p[col] = sum_f u[f] * Wm[f][col]  (per-lane 4-feat partial, then 64-lane butterfly)
  float p[8];
#pragma unroll
  for (int col = 0; col < 8; col++) {
    float4 w = *(const float4*)&wmf[col * 256 + f0];
    p[col] = a0 * w.x + a1 * w.y + a2 * w.z + a3 * w.w;
  }
#pragma unroll
  for (int m = 1; m < 64; m <<= 1) {
#pragma unroll
    for (int col = 0; col < 8; col++) p[col] += __shfl_xor(p[col], m, 64);
  }
  if (lane == 0) {
    float4 o0, o1;
    o0.x = lrelu(p[0] + bmf[0]); o0.y = lrelu(p[1] + bmf[1]);
    o0.z = lrelu(p[2] + bmf[2]); o0.w = lrelu(p[3] + bmf[3]);
    o1.x = lrelu(p[4] + bmf[4]); o1.y = lrelu(p[5] + bmf[5]);
    o1.z = lrelu(p[6] + bmf[6]); o1.w = lrelu(p[7] + bmf[7]);
    *(float4*)(out + (long)node * 8) = o0;
    *(float4*)(out + (long)node * 8 + 4) = o1;
  }
}

// ---------------- central-node MLP (f32 in, f32 out) ----------------
__global__ __launch_bounds__(128) void mlp_kernel(
    const float* __restrict__ outbuf, const int* __restrict__ central,
    const void* __restrict__ Wp1, const void* __restrict__ bp1,
    const void* __restrict__ Wp2, const void* __restrict__ bp2,
    float* __restrict__ logits, const int* __restrict__ flagp) {
  __shared__ float h1[128];
  __shared__ float o[8];
  bool isbf = (*flagp != 0);
  int b = blockIdx.x, tid = threadIdx.x;
  int node = central[b];
  if (tid < 8) o[tid] = outbuf[node * 8 + tid];
  __syncthreads();
  float s = rdf(isbf, bp1, tid);
#pragma unroll
  for (int k = 0; k < 8; k++) s += o[k] * rdf(isbf, Wp1, k * 128 + tid);
  h1[tid] = fmaxf(s, 0.f);
  __syncthreads();
  if (tid < 8) {
    float s2 = rdf(isbf, bp2, tid);
    for (int k = 0; k < 128; k++) s2 += h1[k] * rdf(isbf, Wp2, k * 8 + tid);
    logits[b * 8 + tid] = s2;
  }
}

extern "C" void kernel_launch(void* const* d_in, const int* in_sizes, int n_in,
                              void* d_out, int out_size, void* d_ws, size_t ws_size,
                              hipStream_t stream) {
  const void* x    = d_in[0];
  const void* c    = d_in[1];
  const int* eidx  = (const int*)d_in[2];
  const int* cidx  = (const int*)d_in[3];
  const void* me_x = d_in[4];
  const void* me_c = d_in[5];
  const void* W1e  = d_in[6];
  const void* b1e  = d_in[7];
  const void* e1e  = d_in[8];
  const void* W2e  = d_in[9];
  const void* b2e  = d_in[10];
  const void* e2e  = d_in[11];
  const void* W1c  = d_in[12];
  const void* b1c  = d_in[13];
  const void* e1c  = d_in[14];
  const void* W2c  = d_in[15];
  const void* b2c  = d_in[16];
  const void* e2c  = d_in[17];
  const void* Wm   = d_in[18];
  const void* bm   = d_in[19];
  const void* Wp1  = d_in[20];
  const void* bp1  = d_in[21];
  const void* Wp2  = d_in[22];
  const void* bp2  = d_in[23];

  const int N = in_sizes[0] / 256;   // 50000
  const int E = in_sizes[2] / 2;     // 800000
  const int Cn = in_sizes[3];        // 512
  const int* src = eidx;
  const int* dst = eidx + E;

  char* ws = (char*)d_ws;
  int* deg    = (int*)(ws + 0);          // 200000 B
  int* rowptr = (int*)(ws + 200192);     // 200004 B
  int* cursor = (int*)(ws + 400384);     // 200000 B
  int* colarr = (int*)(ws + 600576);     // 3200000 B + 192 B zero pad
  u16* tbuf   = (u16*)(ws + 3800832);    // 25600000 B  [N,256] bf16
  u16* ubuf   = (u16*)(ws + 29400832);   // 25600000 B  [N,256] bf16
  u16* wt_all = (u16*)(ws + 55000832);   // 172032 B
  int* flag   = (int*)(ws + 55172864);   // 4 B
  int* bsum   = (int*)(ws + 55173120);   // 256 B
  int* boff   = (int*)(ws + 55173376);   // 256 B

  u16* w1e_t = wt_all + 0;       // [32][128][8]  k8-major, 64 KB
  u16* w1c_t = wt_all + 32768;   // [16][128][8]  k8-major, 32 KB
  u16* w2e_t = wt_all + 49152;   // [16][128][8]
  u16* w2c_t = wt_all + 65536;   // [16][128][8]
  u16* wm_t  = wt_all + 81920;   // [16][256]  (rows 8..15 are zeros)
  const u16* zrow = wt_all + 83968;  // = wm_t + 8*256: guaranteed-zero 512 B row

  // init: zero deg + colarr pad (48 entries) + dtype detect
  init_kernel<<<(N + 1023) / 1024, 256, 0, stream>>>(deg, N, (const u16*)x, flag,
                                                     colarr, E);

  // CSR build
  hist_kernel<<<(E + 255) / 256, 256, 0, stream>>>(dst, E, deg);
  int PB = (N + SCB - 1) / SCB;  // 49
  scan_phaseA<<<PB, 256, 0, stream>>>(deg, bsum, N);
  scan_phaseB<<<1, 64, 0, stream>>>(bsum, boff, PB, rowptr, N);
  scan_phaseC<<<PB, 256, 0, stream>>>(deg, boff, rowptr, cursor, N);
  fill_kernel<<<(E + 255) / 256, 256, 0, stream>>>(src, dst, E, cursor, colarr);

  // weight transposes
  TWDesc td;
  td.W[0] = W1e; td.K[0] = 256; td.Nc[0] = 128;
  td.W[1] = W1c; td.K[1] = 128; td.Nc[1] = 128;
  td.W[2] = W2e; td.K[2] = 128; td.Nc[2] = 128;
  td.W[3] = W2c; td.K[3] = 128; td.Nc[3] = 128;
  td.W[4] = Wm;  td.K[4] = 256; td.Nc[4] = 8;
  td.base[0] = 0; td.base[1] = 32768; td.base[2] = 49152;
  td.base[3] = 65536; td.base[4] = 81920; td.base[5] = 86016;
  transpose_all<<<(86016 + 255) / 256, 256, 0, stream>>>(td, wt_all, flag);

  int gb = (N + 63) / 64;  // 782
  // layer 1 (e/c split; 32KB K-chunked LDS-staged B)
  gemm_l1<<<2 * gb, 256, 0, stream>>>(x, c, me_x, me_c, w1e_t, w1c_t, N, gb, tbuf, flag);
  agg_kernel<<<(N + 3) / 4, 256, 0, stream>>>(tbuf, rowptr, colarr,
      e1e, e1c, b1e, b1c, ubuf, N, zrow, flag);
  // layer 2 (e/c split; LDS-staged B)
  gemm_l2<<<2 * gb, 256, 0, stream>>>(ubuf, w2e_t, w2c_t, N, gb, tbuf);
  // agg2 + head fused -> d_out[0 : N*8] f32
  agg_head<<<(N + 3) / 4, 256, 0, stream>>>(tbuf, rowptr, colarr,
      e2e, e2c, b2e, b2c, wm_t, bm, (float*)d_out, N, zrow, flag);
  // central MLP -> d_out[N*8 : ...]
  mlp_kernel<<<Cn, 128, 0, stream>>>((const float*)d_out, cidx,
      Wp1, bp1, Wp2, bp2, (float*)d_out + (size_t)N * 8, flag);
}

// Round 13
// 393.132 us; speedup vs baseline: 1.2739x; 1.0092x over previous
//
#include <hip/hip_runtime.h>

typedef unsigned short u16;
typedef __attribute__((ext_vector_type(8))) short short8;
typedef __attribute__((ext_vector_type(4))) float floatx4;
typedef __attribute__((ext_vector_type(2))) float floatx2;

__device__ __forceinline__ float b2f(unsigned int ubits) {
  union { unsigned int i; float f; } cv; cv.i = ubits << 16; return cv.f;
}
__device__ __forceinline__ float hi2f(unsigned int u) {
  union { unsigned int i; float f; } cv; cv.i = u & 0xffff0000u; return cv.f;
}
__device__ __forceinline__ float lo2f(unsigned int u) {
  union { unsigned int i; float f; } cv; cv.i = u << 16; return cv.f;
}
__device__ __forceinline__ u16 f2b(float f) {
  unsigned int u = __builtin_bit_cast(unsigned int, f);
  u += 0x7fffu + ((u >> 16) & 1u);   // RNE
  return (u16)(u >> 16);
}
__device__ __forceinline__ float lrelu(float v) { return v > 0.f ? v : 0.2f * v; }
__device__ __forceinline__ float rdf(bool isbf, const void* p, int idx) {
  return isbf ? b2f((unsigned int)((const u16*)p)[idx]) : ((const float*)p)[idx];
}
__device__ __forceinline__ floatx2 up2(unsigned int u) {
  return (floatx2){lo2f(u), hi2f(u)};   // (even feat, odd feat) -> v_pk_add_f32
}

// ---------------- init: zero deg + colarr pad (48) + dtype detect (block 0) ----------------
__global__ __launch_bounds__(256) void init_kernel(int* __restrict__ deg, int n,
                                                   const u16* __restrict__ probe,
                                                   int* __restrict__ flag,
                                                   int* __restrict__ colarr, int E) {
  int i0 = (blockIdx.x * 256 + threadIdx.x) * 4;
  if (i0 + 3 < n) {
    *(int4*)(deg + i0) = make_int4(0, 0, 0, 0);
  } else {
    for (int j = 0; j < 4; j++) if (i0 + j < n) deg[i0 + j] = 0;
  }
  if (blockIdx.x == 0) {
    if (threadIdx.x >= 64 && threadIdx.x < 112) colarr[E + (int)threadIdx.x - 64] = 0;
    if (threadIdx.x < 64) {
      int lane = threadIdx.x;
      int cnt = 0;
      for (int i = lane; i < 256; i += 64) {
        unsigned int u = probe[i];
        unsigned int e = (u >> 7) & 0xFFu;
        if ((u & 0x7fffu) == 0 || (e >= 60 && e <= 191)) cnt++;
      }
#pragma unroll
      for (int off = 32; off; off >>= 1) cnt += __shfl_down(cnt, off, 64);
      if (lane == 0) *flag = (cnt >= 240) ? 1 : 0;
    }
  }
}

// ---------------- CSR build ----------------
__global__ __launch_bounds__(256) void hist_kernel(const int* __restrict__ dst, int E,
                                                   int* __restrict__ deg) {
  int i = blockIdx.x * 256 + threadIdx.x;
  if (i < E) atomicAdd(deg + dst[i], 1);
}

#define SCB 1024  // nodes per scan block (256 thr x 4)

__global__ __launch_bounds__(256) void scan_phaseA(const int* __restrict__ deg,
                                                   int* __restrict__ bsum, int n) {
  int i0 = blockIdx.x * SCB + threadIdx.x * 4;
  int s = 0;
  if (i0 + 3 < n) {
    int4 v = *(const int4*)(deg + i0);
    s = v.x + v.y + v.z + v.w;
  } else {
    for (int j = 0; j < 4; j++) if (i0 + j < n) s += deg[i0 + j];
  }
#pragma unroll
  for (int off = 32; off; off >>= 1) s += __shfl_down(s, off, 64);
  __shared__ int ws4[4];
  int lane = threadIdx.x & 63, wid = threadIdx.x >> 6;
  if (lane == 0) ws4[wid] = s;
  __syncthreads();
  if (threadIdx.x == 0) bsum[blockIdx.x] = ws4[0] + ws4[1] + ws4[2] + ws4[3];
}

__global__ void scan_phaseB(const int* __restrict__ bsum, int* __restrict__ boff,
                            int PB, int* __restrict__ rowptr, int n) {
  int lane = threadIdx.x;  // 64, PB <= 64
  int v = (lane < PB) ? bsum[lane] : 0;
  int incl = v;
#pragma unroll
  for (int off = 1; off < 64; off <<= 1) {
    int t = __shfl_up(incl, off, 64);
    if (lane >= off) incl += t;
  }
  if (lane < PB) boff[lane] = incl - v;
  if (lane == 63) rowptr[n] = incl;
}

__global__ __launch_bounds__(256) void scan_phaseC(const int* __restrict__ deg,
                                                   const int* __restrict__ boff,
                                                   int* __restrict__ rowptr,
                                                   int* __restrict__ cursor, int n) {
  int i0 = blockIdx.x * SCB + threadIdx.x * 4;
  int v0 = 0, v1 = 0, v2 = 0, v3 = 0;
  if (i0 + 3 < n) {
    int4 v = *(const int4*)(deg + i0);
    v0 = v.x; v1 = v.y; v2 = v.z; v3 = v.w;
  } else {
    if (i0 < n) v0 = deg[i0];
    if (i0 + 1 < n) v1 = deg[i0 + 1];
    if (i0 + 2 < n) v2 = deg[i0 + 2];
    if (i0 + 3 < n) v3 = deg[i0 + 3];
  }
  int local = v0 + v1 + v2 + v3;
  int lane = threadIdx.x & 63, wid = threadIdx.x >> 6;
  int incl = local;
#pragma unroll
  for (int off = 1; off < 64; off <<= 1) {
    int t = __shfl_up(incl, off, 64);
    if (lane >= off) incl += t;
  }
  __shared__ int ws4[4];
  if (lane == 63) ws4[wid] = incl;
  __syncthreads();
  int woff = 0;
  for (int w = 0; w < wid; w++) woff += ws4[w];
  int run = boff[blockIdx.x] + woff + incl - local;
  if (i0 < n)     { rowptr[i0] = run;     cursor[i0] = run; }     run += v0;
  if (i0 + 1 < n) { rowptr[i0 + 1] = run; cursor[i0 + 1] = run; } run += v1;
  if (i0 + 2 < n) { rowptr[i0 + 2] = run; cursor[i0 + 2] = run; } run += v2;
  if (i0 + 3 < n) { rowptr[i0 + 3] = run; cursor[i0 + 3] = run; }
}

__global__ __launch_bounds__(256) void fill_kernel(const int* __restrict__ src,
                                                   const int* __restrict__ dst, int E,
                                                   int* __restrict__ cursor,
                                                   int* __restrict__ colarr) {
  int i = blockIdx.x * 256 + threadIdx.x;
  if (i < E) {
    int p = atomicAdd(cursor + dst[i], 1);
    colarr[p] = src[i];
  }
}

// -------- all weight transposes in one kernel ----------------------------------------
// segments 0..3 (GEMM B operands): k8-major layout  [K/8][128][8]
// segment 4 (Wm for agg_head): [16][256], rows 8..15 zero (zrow lives there).
struct TWDesc {
  const void* W[5];
  int K[5];
  int Nc[5];
  int base[6];  // u16 offsets
};

__global__ __launch_bounds__(256) void transpose_all(TWDesc d, u16* __restrict__ out,
                                                     const int* __restrict__ flagp) {
  bool isbf = (*flagp != 0);
  int idx = blockIdx.x * 256 + threadIdx.x;
  if (idx >= d.base[5]) return;
  int s = 0;
  while (idx >= d.base[s + 1]) s++;
  int local = idx - d.base[s];
  if (s < 4) {
    int k8 = local >> 10;          // local / (128*8)
    int rem = local & 1023;
    int col = rem >> 3;
    int k7 = rem & 7;
    int k = k8 * 8 + k7;
    out[idx] = f2b(rdf(isbf, d.W[s], k * 128 + col));   // Nc = 128 for all four
  } else {
    int nn = local >> 8;           // local / 256
    int k = local & 255;
    out[idx] = (nn < d.Nc[4]) ? f2b(rdf(isbf, d.W[4], k * d.Nc[4] + nn)) : (u16)0;
  }
}

// ---------------- A-fragment load (runtime dtype, exact-zero -> me) ----------------
__device__ __forceinline__ short8 load_a_me(const void* Av, int lda, const void* me,
                                            int r, int k0, int q, bool isbf) {
  short8 a;
  if (isbf) {
    a = *(const short8*)((const u16*)Av + (long)r * lda + k0 + q * 8);
#pragma unroll
    for (int j = 0; j < 8; j++) {
      if (((u16)a[j] & 0x7fffu) == 0)
        a[j] = (short)((const u16*)me)[k0 + q * 8 + j];
    }
  } else {
    const float* A = (const float*)Av;
    const uint4* p = (const uint4*)(A + (long)r * lda + k0 + q * 8);
    uint4 w0 = p[0];
    uint4 w1 = p[1];
    unsigned int ww[8] = {w0.x, w0.y, w0.z, w0.w, w1.x, w1.y, w1.z, w1.w};
#pragma unroll
    for (int j = 0; j < 8; j++) {
      if ((ww[j] & 0x7fffffffu) == 0)
        a[j] = (short)f2b(((const float*)me)[k0 + q * 8 + j]);
      else
        a[j] = (short)f2b(__builtin_bit_cast(float, ww[j]));
    }
  }
  return a;
}

// ------------- layer-1 GEMM, e/c split across blocks; 512-thread blocks (8 waves,
// 128 rows) amortize each 32KB B-stage over 2x rows; K-chunked staging (K=128/stage):
// blocks [0,gb): tbuf[r][0:128]   = x' @ W1e  (K=256, two stages)
// blocks [gb,2gb): tbuf[r][128:256] = c' @ W1c  (K=128, one stage)
__global__ __launch_bounds__(512) void gemm_l1(
    const void* __restrict__ x, const void* __restrict__ cc,
    const void* __restrict__ mex, const void* __restrict__ mec,
    const u16* __restrict__ w1e_t, const u16* __restrict__ w1c_t,
    int M, int gb, u16* __restrict__ tb, const int* __restrict__ flagp) {
  __shared__ __align__(16) u16 bs[16384];  // 32 KB
  bool isbf = (*flagp != 0);
  bool isC = (blockIdx.x >= (unsigned)gb);
  int bid = isC ? (int)blockIdx.x - gb : (int)blockIdx.x;
  int tid = threadIdx.x;
  int wid = tid >> 6;          // 0..7
  int lane = tid & 63;
  int l15 = lane & 15;
  int q = lane >> 4;
  int row0 = bid * 128 + wid * 16;
  int r = row0 + l15;
  if (r >= M) r = M - 1;

  const void* A  = isC ? cc : x;
  const void* me = isC ? mec : mex;
  const u16* wt  = isC ? w1c_t : w1e_t;
  int K    = isC ? 128 : 256;
  int cofs = isC ? 128 : 0;

  floatx4 acc[8];
#pragma unroll
  for (int n = 0; n < 8; n++) acc[n] = (floatx4){0, 0, 0, 0};

  for (int kt = 0; kt < K; kt += 128) {
    // stage B chunk [kt, kt+128): contiguous 32 KB in k8-major layout
    const u16* wsrc = wt + (kt >> 3) * 1024;
    for (int i = tid; i < 2048; i += 512)
      *(uint4*)(bs + i * 8) = *(const uint4*)(wsrc + i * 8);
    __syncthreads();

    for (int k0 = 0; k0 < 128; k0 += 32) {
      short8 a = load_a_me(A, K, me, r, kt + k0, q, isbf);
      const u16* bb = bs + ((k0 >> 3) + q) * 1024 + l15 * 8;
#pragma unroll
      for (int n = 0; n < 8; n++) {
        short8 b = *(const short8*)(bb + n * 128);
        acc[n] = __builtin_amdgcn_mfma_f32_16x16x32_bf16(a, b, acc[n], 0, 0, 0);
      }
    }
    __syncthreads();  // protect bs before next-chunk overwrite
  }
#pragma unroll
  for (int n = 0; n < 8; n++)
#pragma unroll
    for (int rr = 0; rr < 4; rr++) {
      int row = row0 + q * 4 + rr;
      if (row < M) tb[(long)row * 256 + cofs + n * 16 + l15] = f2b(acc[n][rr]);
    }
}

// ------------- layer-2 GEMM, e/c split across blocks; 512-thread blocks (128 rows);
// B staged in LDS (k8-major, 32KB): reads row-major ubuf, writes row-major tbuf.
__global__ __launch_bounds__(512) void gemm_l2(
    const u16* __restrict__ u,
    const u16* __restrict__ w2e_t, const u16* __restrict__ w2c_t,
    int M, int gb, u16* __restrict__ tb) {
  __shared__ __align__(16) u16 bs[16384];  // 32 KB
  bool isC = (blockIdx.x >= (unsigned)gb);
  int bid = isC ? (int)blockIdx.x - gb : (int)blockIdx.x;
  int tid = threadIdx.x;
  int wid = tid >> 6;          // 0..7
  int lane = tid & 63;
  int l15 = lane & 15;
  int q = lane >> 4;
  int row0 = bid * 128 + wid * 16;
  int r = row0 + l15;
  if (r >= M) r = M - 1;

  const u16* wt = isC ? w2c_t : w2e_t;
  int aofs = isC ? 128 : 0;

  for (int i = tid; i < 2048; i += 512)
    *(uint4*)(bs + i * 8) = *(const uint4*)(wt + i * 8);
  __syncthreads();

  floatx4 acc[8];
#pragma unroll
  for (int n = 0; n < 8; n++) acc[n] = (floatx4){0, 0, 0, 0};

  for (int k0 = 0; k0 < 128; k0 += 32) {
    short8 a = *(const short8*)(u + (long)r * 256 + aofs + k0 + q * 8);
    const u16* bb = bs + ((k0 >> 3) + q) * 1024 + l15 * 8;
#pragma unroll
    for (int n = 0; n < 8; n++) {
      short8 b = *(const short8*)(bb + n * 128);
      acc[n] = __builtin_amdgcn_mfma_f32_16x16x32_bf16(a, b, acc[n], 0, 0, 0);
    }
  }
#pragma unroll
  for (int n = 0; n < 8; n++)
#pragma unroll
    for (int rr = 0; rr < 4; rr++) {
      int row = row0 + q * 4 + rr;
      if (row < M) tb[(long)row * 256 + aofs + n * 16 + l15] = f2b(acc[n][rr]);
    }
}

// ===== gather core: round-0 layout (64 lanes x uint2 = one coalesced 512B row/instr).
// Depth-8 software pipeline: 8 row-gathers in flight per wave; col indices via SCALAR
// loads (wave-uniform -> s_load, SGPR-resident, zero VGPR cost; no clamps thanks to the
// zero pad on colarr); ONE masked final batch (tail -> guaranteed-zero row).
__device__ __forceinline__ void gin_gather8(
    const u16* __restrict__ t, const int* __restrict__ rowptr,
    const int* __restrict__ colarr, const u16* __restrict__ zrow,
    int node, long fbB, floatx2& s01, floatx2& s23) {
  const char* base = (const char*)t + fbB;   // per-lane feature base
  const char* zb = (const char*)zrow + fbB;  // zero row
  s01 = (floatx2){0.f, 0.f};
  s23 = (floatx2){0.f, 0.f};
  int eu  = __builtin_amdgcn_readfirstlane(rowptr[node]);
  int e1u = __builtin_amdgcn_readfirstlane(rowptr[node + 1]);
  int c0 = colarr[eu],     c1 = colarr[eu + 1], c2 = colarr[eu + 2], c3 = colarr[eu + 3];
  int c4 = colarr[eu + 4], c5 = colarr[eu + 5], c6 = colarr[eu + 6], c7 = colarr[eu + 7];
  int eb = eu;
  for (; eb + 8 <= e1u; eb += 8) {
    uint2 w0 = *(const uint2*)(base + ((long)c0 << 9));
    uint2 w1 = *(const uint2*)(base + ((long)c1 << 9));
    uint2 w2 = *(const uint2*)(base + ((long)c2 << 9));
    uint2 w3 = *(const uint2*)(base + ((long)c3 << 9));
    uint2 w4 = *(const uint2*)(base + ((long)c4 << 9));
    uint2 w5 = *(const uint2*)(base + ((long)c5 << 9));
    uint2 w6 = *(const uint2*)(base + ((long)c6 << 9));
    uint2 w7 = *(const uint2*)(base + ((long)c7 << 9));
    int n0 = colarr[eb + 8],  n1 = colarr[eb + 9],  n2 = colarr[eb + 10], n3 = colarr[eb + 11];
    int n4 = colarr[eb + 12], n5 = colarr[eb + 13], n6 = colarr[eb + 14], n7 = colarr[eb + 15];
    s01 += up2(w0.x); s23 += up2(w0.y);
    s01 += up2(w1.x); s23 += up2(w1.y);
    s01 += up2(w2.x); s23 += up2(w2.y);
    s01 += up2(w3.x); s23 += up2(w3.y);
    s01 += up2(w4.x); s23 += up2(w4.y);
    s01 += up2(w5.x); s23 += up2(w5.y);
    s01 += up2(w6.x); s23 += up2(w6.y);
    s01 += up2(w7.x); s23 += up2(w7.y);
    c0 = n0; c1 = n1; c2 = n2; c3 = n3;
    c4 = n4; c5 = n5; c6 = n6; c7 = n7;
  }
  int rem = e1u - eb;  // 0..7
  if (rem > 0) {
    const char* p0 = base + ((long)c0 << 9);
    const char* p1 = (1 < rem) ? base + ((long)c1 << 9) : zb;
    const char* p2 = (2 < rem) ? base + ((long)c2 << 9) : zb;
    const char* p3 = (3 < rem) ? base + ((long)c3 << 9) : zb;
    const char* p4 = (4 < rem) ? base + ((long)c4 << 9) : zb;
    const char* p5 = (5 < rem) ? base + ((long)c5 << 9) : zb;
    const char* p6 = (6 < rem) ? base + ((long)c6 << 9) : zb;
    const char* p7 = (7 < rem) ? base + ((long)c7 << 9) : zb;
    uint2 w0 = *(const uint2*)p0;
    uint2 w1 = *(const uint2*)p1;
    uint2 w2 = *(const uint2*)p2;
    uint2 w3 = *(const uint2*)p3;
    uint2 w4 = *(const uint2*)p4;
    uint2 w5 = *(const uint2*)p5;
    uint2 w6 = *(const uint2*)p6;
    uint2 w7 = *(const uint2*)p7;
    s01 += up2(w0.x); s23 += up2(w0.y);
    s01 += up2(w1.x); s23 += up2(w1.y);
    s01 += up2(w2.x); s23 += up2(w2.y);
    s01 += up2(w3.x); s23 += up2(w3.y);
    s01 += up2(w4.x); s23 += up2(w4.y);
    s01 += up2(w5.x); s23 += up2(w5.y);
    s01 += up2(w6.x); s23 += up2(w6.y);
    s01 += up2(w7.x); s23 += up2(w7.y);
  }
}

// ------- agg layer-1 (wave per node, 4 feats/lane; bf16 out) -------
__global__ __launch_bounds__(256) void agg_kernel(
    const u16* __restrict__ t, const int* __restrict__ rowptr, const int* __restrict__ colarr,
    const void* __restrict__ epsE, const void* __restrict__ epsC,
    const void* __restrict__ bE, const void* __restrict__ bC,
    u16* __restrict__ u, int N, const u16* __restrict__ zrow,
    const int* __restrict__ flagp) {
  int node = blockIdx.x * 4 + __builtin_amdgcn_readfirstlane(threadIdx.x >> 6);
  if (node >= N) return;
  bool isbf = (*flagp != 0);
  int lane = threadIdx.x & 63;
  int f0 = lane << 2;
  long fbB = (long)f0 << 1;  // lane*8 bytes
  const u16* tb = t + f0;

  uint2 ps = *(const uint2*)(tb + ((long)node << 8));  // self row, issued early

  floatx2 s01, s23;
  gin_gather8(t, rowptr, colarr, zrow, node, fbB, s01, s23);

  bool isE = (lane < 32);
  float eps2 = 2.0f + rdf(isbf, isE ? epsE : epsC, 0);
  const void* bp = isE ? bE : bC;
  int bi = isE ? f0 : (f0 - 128);
  float a0 = lrelu(s01.x + eps2 * lo2f(ps.x) + rdf(isbf, bp, bi + 0));
  float a1 = lrelu(s01.y + eps2 * hi2f(ps.x) + rdf(isbf, bp, bi + 1));
  float a2 = lrelu(s23.x + eps2 * lo2f(ps.y) + rdf(isbf, bp, bi + 2));
  float a3 = lrelu(s23.y + eps2 * hi2f(ps.y) + rdf(isbf, bp, bi + 3));
  uint2 o;
  o.x = ((unsigned int)f2b(a1) << 16) | f2b(a0);
  o.y = ((unsigned int)f2b(a3) << 16) | f2b(a2);
  *(uint2*)(u + ((long)node << 8) + f0) = o;
}

// ------- agg layer-2 + head fused: out[node] = lrelu(u @ Wm + bm) -------
__global__ __launch_bounds__(256) void agg_head(
    const u16* __restrict__ t, const int* __restrict__ rowptr, const int* __restrict__ colarr,
    const void* __restrict__ epsE, const void* __restrict__ epsC,
    const void* __restrict__ bE, const void* __restrict__ bC,
    const u16* __restrict__ wm_t, const void* __restrict__ bm,
    float* __restrict__ out, int N, const u16* __restrict__ zrow,
    const int* __restrict__ flagp) {
  __shared__ float wmf[2048];  // [col][f] f32, from wm_t [16][256] (cols 0..7)
  __shared__ float bmf[8];
  bool isbf = (*flagp != 0);
  int tid = threadIdx.x;
  for (int i = tid; i < 2048; i += 256) wmf[i] = b2f((unsigned int)wm_t[i]);
  if (tid < 8) bmf[tid] = rdf(isbf, bm, tid);
  __syncthreads();

  int node = blockIdx.x * 4 + __builtin_amdgcn_readfirstlane(tid >> 6);
  if (node >= N) return;
  int lane = tid & 63;
  int f0 = lane << 2;
  long fbB = (long)f0 << 1;
  const u16* tb = t + f0;

  uint2 ps = *(const uint2*)(tb + ((long)node << 8));  // self row, issued early

  floatx2 s01, s23;
  gin_gather8(t, rowptr, colarr, zrow, node, fbB, s01, s23);

  bool isE = (lane < 32);
  float eps2 = 2.0f + rdf(isbf, isE ? epsE : epsC, 0);
  const void* bp = isE ? bE : bC;
  int bi = isE ? f0 : (f0 - 128);
  float a0 = lrelu(s01.x + eps2 * lo2f(ps.x) + rdf(isbf, bp, bi + 0));
  float a1 = lrelu(s01.y + eps2 * hi2f(ps.x) + rdf(isbf, bp, bi + 1));
  float a2 = lrelu(s23.x + eps2 * lo2f(ps.y) + rdf(isbf, bp, bi + 2));
  float a3 = lrelu(s23.y + eps2 * hi2f(ps.y) + rdf(isbf, bp, bi + 3));

  // head: p[col] = sum_f u[f] * Wm[f][col]  (per-lane 4-feat partial, then 64-lane butterfly)
  float p[8];
#pragma unroll
  for (int col = 0; col < 8; col++) {
    float4 w = *(const float4*)&wmf[col * 256 + f0];
    p[col] = a0 * w.x + a1 * w.y + a2 * w.z + a3 * w.w;
  }
#pragma unroll
  for (int m = 1; m < 64; m <<= 1) {
#pragma unroll
    for (int col = 0; col < 8; col++) p[col] += __shfl_xor(p[col], m, 64);
  }
  if (lane == 0) {
    float4 o0, o1;
    o0.x = lrelu(p[0] + bmf[0]); o0.y = lrelu(p[1] + bmf[1]);
    o0.z = lrelu(p[2] + bmf[2]); o0.w = lrelu(p[3] + bmf[3]);
    o1.x = lrelu(p[4] + bmf[4]); o1.y = lrelu(p[5] + bmf[5]);
    o1.z = lrelu(p[6] + bmf[6]); o1.w = lrelu(p[7] + bmf[7]);
    *(float4*)(out + (long)node * 8) = o0;
    *(float4*)(out + (long)node * 8 + 4) = o1;
  }
}

// ---------------- central-node MLP (f32 in, f32 out) ----------------
__global__ __launch_bounds__(128) void mlp_kernel(
    const float* __restrict__ outbuf, const int* __restrict__ central,
    const void* __restrict__ Wp1, const void* __restrict__ bp1,
    const void* __restrict__ Wp2, const void* __restrict__ bp2,
    float* __restrict__ logits, const int* __restrict__ flagp) {
  __shared__ float h1[128];
  __shared__ float o[8];
  bool isbf = (*flagp != 0);
  int b = blockIdx.x, tid = threadIdx.x;
  int node = central[b];
  if (tid < 8) o[tid] = outbuf[node * 8 + tid];
  __syncthreads();
  float s = rdf(isbf, bp1, tid);
#pragma unroll
  for (int k = 0; k < 8; k++) s += o[k] * rdf(isbf, Wp1, k * 128 + tid);
  h1[tid] = fmaxf(s, 0.f);
  __syncthreads();
  if (tid < 8) {
    float s2 = rdf(isbf, bp2, tid);
    for (int k = 0; k < 128; k++) s2 += h1[k] * rdf(isbf, Wp2, k * 8 + tid);
    logits[b * 8 + tid] = s2;
  }
}

extern "C" void kernel_launch(void* const* d_in, const int* in_sizes, int n_in,
                              void* d_out, int out_size, void* d_ws, size_t ws_size,
                              hipStream_t stream) {
  const void* x    = d_in[0];
  const void* c    = d_in[1];
  const int* eidx  = (const int*)d_in[2];
  const int* cidx  = (const int*)d_in[3];
  const void* me_x = d_in[4];
  const void* me_c = d_in[5];
  const void* W1e  = d_in[6];
  const void* b1e  = d_in[7];
  const void* e1e  = d_in[8];
  const void* W2e  = d_in[9];
  const void* b2e  = d_in[10];
  const void* e2e  = d_in[11];
  const void* W1c  = d_in[12];
  const void* b1c  = d_in[13];
  const void* e1c  = d_in[14];
  const void* W2c  = d_in[15];
  const void* b2c  = d_in[16];
  const void* e2c  = d_in[17];
  const void* Wm   = d_in[18];
  const void* bm   = d_in[19];
  const void* Wp1  = d_in[20];
  const void* bp1  = d_in[21];
  const void* Wp2  = d_in[22];
  const void* bp2  = d_in[23];

  const int N = in_sizes[0] / 256;   // 50000
  const int E = in_sizes[2] / 2;     // 800000
  const int Cn = in_sizes[3];        // 512
  const int* src = eidx;
  const int* dst = eidx + E;

  char* ws = (char*)d_ws;
  int* deg    = (int*)(ws + 0);          // 200000 B
  int* rowptr = (int*)(ws + 200192);     // 200004 B
  int* cursor = (int*)(ws + 400384);     // 200000 B
  int* colarr = (int*)(ws + 600576);     // 3200000 B + 192 B zero pad
  u16* tbuf   = (u16*)(ws + 3800832);    // 25600000 B  [N,256] bf16
  u16* ubuf   = (u16*)(ws + 29400832);   // 25600000 B  [N,256] bf16
  u16* wt_all = (u16*)(ws + 55000832);   // 172032 B
  int* flag   = (int*)(ws + 55172864);   // 4 B
  int* bsum   = (int*)(ws + 55173120);   // 256 B
  int* boff   = (int*)(ws + 55173376);   // 256 B

  u16* w1e_t = wt_all + 0;       // [32][128][8]  k8-major, 64 KB
  u16* w1c_t = wt_all + 32768;   // [16][128][8]  k8-major, 32 KB
  u16* w2e_t = wt_all + 49152;   // [16][128][8]
  u16* w2c_t = wt_all + 65536;   // [16][128][8]
  u16* wm_t  = wt_all + 81920;   // [16][256]  (rows 8..15 are zeros)
  const u16* zrow = wt_all + 83968;  // = wm_t + 8*256: guaranteed-zero 512 B row

  // init: zero deg + colarr pad (48 entries) + dtype detect
  init_kernel<<<(N + 1023) / 1024, 256, 0, stream>>>(deg, N, (const u16*)x, flag,
                                                     colarr, E);

  // CSR build
  hist_kernel<<<(E + 255) / 256, 256, 0, stream>>>(dst, E, deg);
  int PB = (N + SCB - 1) / SCB;  // 49
  scan_phaseA<<<PB, 256, 0, stream>>>(deg, bsum, N);
  scan_phaseB<<<1, 64, 0, stream>>>(bsum, boff, PB, rowptr, N);
  scan_phaseC<<<PB, 256, 0, stream>>>(deg, boff, rowptr, cursor, N);
  fill_kernel<<<(E + 255) / 256, 256, 0, stream>>>(src, dst, E, cursor, colarr);

  // weight transposes
  TWDesc td;
  td.W[0] = W1e; td.K[0] = 256; td.Nc[0] = 128;
  td.W[1] = W1c; td.K[1] = 128; td.Nc[1] = 128;
  td.W[2] = W2e; td.K[2] = 128; td.Nc[2] = 128;
  td.W[3] = W2c; td.K[3] = 128; td.Nc[3] = 128;
  td.W[4] = Wm;  td.K[4] = 256; td.Nc[4] = 8;
  td.base[0] = 0; td.base[1] = 32768; td.base[2] = 49152;
  td.base[3] = 65536; td.base[4] = 81920; td.base[5] = 86016;
  transpose_all<<<(86016 + 255) / 256, 256, 0, stream>>>(td, wt_all, flag);

  int gb2 = (N + 127) / 128;  // 391 (128 rows/block)
  // layer 1 (e/c split; 512-thr blocks; 32KB K-chunked LDS-staged B)
  gemm_l1<<<2 * gb2, 512, 0, stream>>>(x, c, me_x, me_c, w1e_t, w1c_t, N, gb2, tbuf, flag);
  agg_kernel<<<(N + 3) / 4, 256, 0, stream>>>(tbuf, rowptr, colarr,
      e1e, e1c, b1e, b1c, ubuf, N, zrow, flag);
  // layer 2 (e/c split; 512-thr blocks; LDS-staged B)
  gemm_l2<<<2 * gb2, 512, 0, stream>>>(ubuf, w2e_t, w2c_t, N, gb2, tbuf);
  // agg2 + head fused -> d_out[0 : N*8] f32
  agg_head<<<(N + 3) / 4, 256, 0, stream>>>(tbuf, rowptr, colarr,
      e2e, e2c, b2e, b2c, wm_t, bm, (float*)d_out, N, zrow, flag);
  // central MLP -> d_out[N*8 : ...]
  mlp_kernel<<<Cn, 128, 0, stream>>>((const float*)d_out, cidx,
      Wp1, bp1, Wp2, bp2, (float*)d_out + (size_t)N * 8, flag);
}